// Round 10
// baseline (4260.801 us; speedup 1.0000x reference)
//
#include <hip/hip_runtime.h>
#include <hip/hip_bf16.h>

typedef __attribute__((ext_vector_type(8))) short short8;
typedef __attribute__((ext_vector_type(4))) float f32x4;
typedef __attribute__((ext_vector_type(4))) unsigned int uint4v;

__device__ __forceinline__ unsigned short f2bf(float f) {
  unsigned u = __builtin_bit_cast(unsigned, f);
  u = (u + 0x7FFFu + ((u >> 16) & 1u)) >> 16;
  return (unsigned short)u;
}
__device__ __forceinline__ float bf2f(unsigned short h) {
  unsigned u = ((unsigned)h) << 16;
  return __builtin_bit_cast(float, u);
}
__device__ __forceinline__ unsigned pk_bf16(float a, float b) {
  __hip_bfloat162 h = __float22bfloat162_rn(make_float2(a, b));
  unsigned u;
  __builtin_memcpy(&u, &h, 4);
  return u;
}

// ================= halo-staged MFMA conv engine (v2: aligned LDS) =========
// Stages the input tile ONCE per 32-ci chunk (with +-1 halo) into LDS; all
// taps read shifted rows from the same staged buffer. Row stride 40 ushorts
// (80 B, 16B-aligned) -> B-fragment read is ONE ds_read_b128.
// CT=0: 3x3 s1 conv (9 taps). CT=1: convT 4x4 s2 (16 taps, 4 phases
// accumulated in-block, 2x2 quad epilogue). M = TMT*16 couts/block.
template<int TMT, int CT, bool SPLIT, bool RELU_IN, bool RELU_OUT, bool BIAS>
__global__ __launch_bounds__(256, (CT == 1) ? 3 : 4) void k_mfhalo(
    const float* __restrict__ in, const unsigned short* __restrict__ wp,
    const float* __restrict__ bias, float* __restrict__ out,
    int Ci, int inW, int inH, int pWSH, int pHWSH,
    int Co, int ntt, unsigned syp, unsigned sxp, int CoSt) {
  constexpr int NTAP = (CT == 1) ? 16 : 9;
  constexpr int NPH  = (CT == 1) ? 4 : 1;
  constexpr int NTO  = (TMT == 4) ? 4 : 2;
  constexpr int HSTR = 40;                  // row stride (ushorts), 80B aligned
  constexpr int PLH  = 224 * HSTR;          // plane stride (ushorts)
  const int tid = threadIdx.x, lane = tid & 63, wave = tid >> 6;

  int bx = blockIdx.x;
  const int gx = gridDim.x;
  if ((gx & 7) == 0) bx = (bx & 7) * (gx >> 3) + (bx >> 3);
  const int n0  = bx * 64;
  const int coG = blockIdx.y;

  const int pW  = 1 << pWSH;
  const int pHW = 1 << pHWSH;
  const int W = inW, H = inH;
  const int inHW = W * H;
  const int img  = n0 >> pHWSH;             // whole block in one image
  const int rem0 = n0 & (pHW - 1);
  const int y0   = rem0 >> pWSH;
  const int x0   = rem0 & (pW - 1);
  const int NR   = (pWSH >= 6) ? 1 : 2;     // image rows covered by 64 px
  const int HWd  = ((pW < 64) ? pW : 64) + 2;
  const int HROWS = (NR + 2) * HWd;         // halo pixels (<=198)
  const int nk32 = Ci >> 5;
  const size_t base_img = (size_t)img * Ci * inHW;

  __shared__ __align__(16) unsigned short Hs[(SPLIT ? 2 : 1) * PLH];

  const int mt  = (TMT == 4) ? wave : (wave & 1);
  const int ntb = (TMT == 4) ? 0 : ((wave >> 1) * 2);
  const int lsh = (pW < 64) ? pWSH : 6;
  const int lxm = (pW < 64) ? (pW - 1) : 63;

  f32x4 acc[NPH * NTO];
#pragma unroll
  for (int u = 0; u < NPH * NTO; ++u) acc[u] = (f32x4){0.f, 0.f, 0.f, 0.f};

  const int srow0 = tid >> 4;               // 0..15
  const int scl   = (tid & 15) * 2;         // ci pair within chunk

  for (int cic = 0; cic < nk32; ++cic) {
    if (cic) __syncthreads();
    // ---- stage halo tile for this 32-ci chunk ----
    {
      const int ci0 = cic * 32;
      int hy = 0, hx = srow0;
      for (int h = srow0; h < HROWS; h += 16) {
        const int iy = y0 - 1 + hy;
        const int ix = x0 - 1 + hx;
        const bool ok = ((unsigned)iy < (unsigned)H) && ((unsigned)ix < (unsigned)W);
        float a = 0.f, b = 0.f;
        if (ok) {
          const float* q = in + base_img + (size_t)(ci0 + scl) * inHW + (size_t)iy * W + ix;
          a = q[0]; b = q[inHW];
        }
        if (RELU_IN) { a = fmaxf(a, 0.f); b = fmaxf(b, 0.f); }
        unsigned hp = pk_bf16(a, b);
        *(unsigned*)&Hs[h * HSTR + scl] = hp;
        if (SPLIT) {
          float h0 = bf2f((unsigned short)hp), h1 = bf2f((unsigned short)(hp >> 16));
          *(unsigned*)&Hs[PLH + h * HSTR + scl] = pk_bf16(a - h0, b - h1);
        }
        hx += 16; if (hx >= HWd) { hx -= HWd; hy++; }
      }
    }
    __syncthreads();
    // ---- all taps from the staged buffer ----
#pragma unroll
    for (int T = 0; T < NTAP; ++T) {
      const int ency = (int)((syp >> (2 * T)) & 3u);
      const int encx = (int)((sxp >> (2 * T)) & 3u);
      size_t abase = (((size_t)coG * ntt + T) * nk32 + cic) * (SPLIT ? 2 : 1) * TMT * 512
                     + (size_t)mt * 512;
      short8 ah = *(const short8*)(wp + abase + (size_t)lane * 8);
      short8 al;
      if (SPLIT) al = *(const short8*)(wp + abase + (size_t)TMT * 512 + (size_t)lane * 8);
      const int ph = (CT == 1) ? (T >> 2) : 0;
#pragma unroll
      for (int u = 0; u < NTO; ++u) {
        const int pnl = (ntb + u) * 16 + (lane & 15);
        const int ly = pnl >> lsh, lx = pnl & lxm;
        const int h = (ly + ency) * HWd + lx + encx;
        short8 bh = *(const short8*)&Hs[h * HSTR + (lane >> 4) * 8];   // ds_read_b128
        f32x4 a = acc[ph * NTO + u];
        a = __builtin_amdgcn_mfma_f32_16x16x32_bf16(ah, bh, a, 0, 0, 0);
        if (SPLIT) {
          short8 bl = *(const short8*)&Hs[PLH + h * HSTR + (lane >> 4) * 8];
          a = __builtin_amdgcn_mfma_f32_16x16x32_bf16(al, bh, a, 0, 0, 0);
          a = __builtin_amdgcn_mfma_f32_16x16x32_bf16(ah, bl, a, 0, 0, 0);
        }
        acc[ph * NTO + u] = a;
      }
    }
  }

  // ---- epilogue ----
  const int outW  = (CT == 1) ? 2 * pW : pW;
  const int outHW = (CT == 1) ? 4 * pHW : pHW;
#pragma unroll
  for (int u = 0; u < NTO; ++u) {
    const int pn = n0 + (ntb + u) * 16 + (lane & 15);
    const int rem2 = pn & (pHW - 1);
    const int y2 = rem2 >> pWSH, x2 = rem2 & (pW - 1);
#pragma unroll
    for (int ph = 0; ph < NPH; ++ph) {
      int oy, ox;
      if (CT == 1) { oy = 2 * y2 + (ph >> 1); ox = 2 * x2 + (ph & 1); }
      else         { oy = y2;                 ox = x2; }
#pragma unroll
      for (int r = 0; r < 4; ++r) {
        const int co = coG * (TMT * 16) + mt * 16 + (lane >> 4) * 4 + r;
        if (co < CoSt) {
          float val = acc[ph * NTO + u][r];
          if (BIAS) val += bias[co];
          if (RELU_OUT) val = fmaxf(val, 0.f);
          out[((size_t)img * Co + co) * outHW + (size_t)oy * outW + ox] = val;
        }
      }
    }
  }
}

// ================= MFMA tap-GEMM conv engine v4 (kept: enc2/3, 1x1) ======
template<int TMT, int MT, int MODE, int ZSP, bool SPLIT, bool RELU_IN, bool RELU_OUT, bool BIAS, int SM>
__global__ __launch_bounds__(256, 4) void k_mfconv(
    const float* __restrict__ in, const unsigned short* __restrict__ wp,
    const float* __restrict__ bias, float* __restrict__ out,
    int Ci, int inW, int inH, int pWSH, int pHWSH,
    int Co, int ntap, int ntt,
    unsigned syp, unsigned sxp,
    int outW, int outHW, int CoSt) {
  const int tid  = threadIdx.x;
  const int lane = tid & 63, wave = tid >> 6;
  const int pW  = 1 << pWSH;
  const int pHW = 1 << pHWSH;
  const int inHW = inW * inH;
  const int nk32 = Ci >> 5;
  const int KS   = (nk32 >= 2) ? 2 : 1;
  const int NITS = 4 * KS;
  const int cpt  = nk32 / KS;
  const int total = ntap * cpt;
  constexpr int TT = TMT * MT;

  int bx = blockIdx.x;
  const int gx = gridDim.x;
  if ((gx & 7) == 0) bx = (bx & 7) * (gx >> 3) + (bx >> 3);
  const int n0  = bx * 64;
  const int coG = blockIdx.y;

  int it0 = 0, itEnd = total;
  if (ZSP > 1) {
    const int per = total / ZSP;
    it0 = blockIdx.z * per;
    itEnd = it0 + per;
  }

  constexpr int NPL = SPLIT ? 2 : 1;
  constexpr int PL = 64 * 70;
  __shared__ __align__(16) unsigned short Bs[2 * NPL * PL];

  const int px  = lane;
  const int p   = n0 + px;
  const int img = p >> pHWSH;
  const int rem = p & (pHW - 1);
  const int y   = rem >> pWSH;
  const int x   = rem & (pW - 1);
  const size_t base_img = (size_t)img * Ci * inHW;

  constexpr int NTO = (TMT == 4) ? 4 : 2;
  const int mt0 = (TMT == 4) ? wave : (wave & 1);
  const int ntb = (TMT == 4) ? 0 : ((wave >> 1) * 2);
  f32x4 acc[MT * NTO];
#pragma unroll
  for (int u = 0; u < MT * NTO; ++u) acc[u] = (f32x4){0.f, 0.f, 0.f, 0.f};

  const int cp = wave;
  float v[16];

  auto ldr = [&](int tap_, int chunk_) {
    const int T = tap_;
    const int dy = (int)((syp >> (2 * T)) & 3u) - 1;
    const int dx = (int)((sxp >> (2 * T)) & 3u) - 1;
    const int ys = (MODE == 2) ? (2 * y + dy) : (y + dy);
    const int xs = (MODE == 2) ? (2 * x + dx) : (x + dx);
    const bool ok = ((unsigned)ys < (unsigned)inH) && ((unsigned)xs < (unsigned)inW);
    const float* __restrict__ ipb = in + base_img + (ptrdiff_t)ys * inW + xs;
    const int ci0 = chunk_ * (KS * 32);
#pragma unroll
    for (int it2 = 0; it2 < 8; ++it2) {
      if (it2 >= NITS) break;
      const int cl = 2 * (cp + 4 * it2);
      float a = 0.f, b = 0.f;
      if (ok) {
        a = ipb[(size_t)(ci0 + cl) * inHW];
        b = ipb[(size_t)(ci0 + cl + 1) * inHW];
      }
      if (RELU_IN) { a = fmaxf(a, 0.f); b = fmaxf(b, 0.f); }
      v[2 * it2] = a; v[2 * it2 + 1] = b;
    }
  };
  auto pwr = [&](int b) {
#pragma unroll
    for (int it2 = 0; it2 < 8; ++it2) {
      if (it2 >= NITS) break;
      const int cl = 2 * (cp + 4 * it2);
      float a = v[2 * it2], c = v[2 * it2 + 1];
      unsigned hp = pk_bf16(a, c);
      *(unsigned*)&Bs[(b * NPL) * PL + px * 70 + cl] = hp;
      if (SPLIT) {
        float h0 = bf2f((unsigned short)hp), h1 = bf2f((unsigned short)(hp >> 16));
        *(unsigned*)&Bs[(b * NPL + 1) * PL + px * 70 + cl] = pk_bf16(a - h0, c - h1);
      }
    }
  };

  int tap = it0 / cpt, chunk = it0 % cpt;
  ldr(tap, chunk);
  pwr(0);
  __syncthreads();

  for (int it = it0; it < itEnd; ++it) {
    const int b = (it - it0) & 1;
    const int T = tap;
    int tap2 = tap, chunk2 = chunk + 1;
    if (chunk2 == cpt) { chunk2 = 0; tap2 = tap + 1; }
    const bool more = (it + 1 < itEnd);
    if (more) ldr(tap2, chunk2);
#pragma unroll
    for (int s = 0; s < 2; ++s) {
      if (s >= KS) break;
      const int cic = chunk * KS + s;
      short8 ah[MT], al[MT];
#pragma unroll
      for (int m = 0; m < MT; ++m) {
        const int mtm = mt0 + m * TMT;
        size_t abase;
        if (SPLIT) abase = ((((size_t)coG * ntt + T) * nk32 + cic) * 2 * TT + mtm) * 512;
        else       abase = ((((size_t)coG * ntt + T) * nk32 + cic) * TT + mtm) * 512;
        ah[m] = *(const short8*)(wp + abase + (size_t)lane * 8);
        if (SPLIT) al[m] = *(const short8*)(wp + abase + (size_t)TT * 512 + (size_t)lane * 8);
      }
      short8 bh[NTO], bl[NTO];
#pragma unroll
      for (int u = 0; u < NTO; ++u) {
        const int row = 16 * (ntb + u) + (lane & 15);
        const unsigned* bp = (const unsigned*)&Bs[(b * NPL) * PL + row * 70 + s * 32 + (lane >> 4) * 8];
        uint4v hv = {bp[0], bp[1], bp[2], bp[3]};
        bh[u] = __builtin_bit_cast(short8, hv);
        if (SPLIT) {
          const unsigned* bpl = bp + (PL >> 1);
          uint4v lv = {bpl[0], bpl[1], bpl[2], bpl[3]};
          bl[u] = __builtin_bit_cast(short8, lv);
        }
      }
#pragma unroll
      for (int m = 0; m < MT; ++m)
#pragma unroll
        for (int u = 0; u < NTO; ++u) {
          f32x4 a = acc[m * NTO + u];
          a = __builtin_amdgcn_mfma_f32_16x16x32_bf16(ah[m], bh[u], a, 0, 0, 0);
          if (SPLIT) {
            a = __builtin_amdgcn_mfma_f32_16x16x32_bf16(al[m], bh[u], a, 0, 0, 0);
            a = __builtin_amdgcn_mfma_f32_16x16x32_bf16(ah[m], bl[u], a, 0, 0, 0);
          }
          acc[m * NTO + u] = a;
        }
    }
    if (more) {
      pwr(b ^ 1);
      __syncthreads();
    }
    tap = tap2; chunk = chunk2;
  }

#pragma unroll
  for (int m = 0; m < MT; ++m) {
    const int mtm = mt0 + m * TMT;
#pragma unroll
    for (int u = 0; u < NTO; ++u) {
      const int nt = ntb + u;
      const int pn = n0 + nt * 16 + (lane & 15);
      const int img2 = pn >> pHWSH;
      const int rem2 = pn & (pHW - 1);
      const int y2 = rem2 >> pWSH, x2 = rem2 & (pW - 1);
#pragma unroll
      for (int r = 0; r < 4; ++r) {
        const int co = coG * (TT * 16) + mtm * 16 + (lane >> 4) * 4 + r;
        if (co < CoSt) {
          float val = acc[m * NTO + u][r];
          if (BIAS) val += bias[co];
          if (RELU_OUT) val = fmaxf(val, 0.f);
          size_t oi = ((size_t)img2 * Co + co) * outHW + (size_t)y2 * outW + x2;
          if (SM == 0) out[oi] = val;
          else if (SM == 1) out[oi] += val;
          else atomicAdd(&out[oi], val);
        }
      }
    }
  }
}

// ================= enc1 as MFMA ===========================================
__global__ __launch_bounds__(256, 4) void k_mfenc1(
    const float* __restrict__ in, const unsigned short* __restrict__ wp,
    const float* __restrict__ bias, float* __restrict__ out) {
  const int tid = threadIdx.x, lane = tid & 63, wave = tid >> 6;
  int bx = blockIdx.x;
  const int gx = gridDim.x;
  if ((gx & 7) == 0) bx = (bx & 7) * (gx >> 3) + (bx >> 3);
  const int n0 = bx * 64;
  const int p = n0 + lane;
  const int img = p >> 14;
  const int rem = p & 16383;
  const int y = rem >> 7, x = rem & 127;
  __shared__ __align__(16) unsigned short Bs[2 * 4480];
  const float* __restrict__ ib = in + (size_t)img * 3 * 65536;
#pragma unroll
  for (int i = 0; i < 8; ++i) {
    const int kk0 = 2 * (wave + 4 * i);
    float vv[2];
#pragma unroll
    for (int q = 0; q < 2; ++q) {
      const int kk = kk0 + q;
      const int tap = kk >> 2, c = kk & 3;
      const int iy = 2 * y + (tap >> 2) - 1, ix = 2 * x + (tap & 3) - 1;
      const bool ok = (c < 3) && ((unsigned)iy < 256u) && ((unsigned)ix < 256u);
      vv[q] = ok ? ib[((size_t)c << 16) + (size_t)iy * 256 + ix] : 0.f;
    }
    unsigned hp = pk_bf16(vv[0], vv[1]);
    *(unsigned*)&Bs[lane * 70 + kk0] = hp;
    float h0 = bf2f((unsigned short)hp), h1 = bf2f((unsigned short)(hp >> 16));
    *(unsigned*)&Bs[4480 + lane * 70 + kk0] = pk_bf16(vv[0] - h0, vv[1] - h1);
  }
  __syncthreads();

  f32x4 acc[8];
#pragma unroll
  for (int u = 0; u < 8; ++u) acc[u] = (f32x4){0.f, 0.f, 0.f, 0.f};
#pragma unroll
  for (int s = 0; s < 2; ++s) {
    short8 ah[2], al[2];
#pragma unroll
    for (int m = 0; m < 2; ++m) {
      const int mtm = wave + m * 4;
      size_t abase = (((size_t)s * 2 + 0) * 8 + mtm) * 512;
      ah[m] = *(const short8*)(wp + abase + (size_t)lane * 8);
      al[m] = *(const short8*)(wp + abase + 8 * 512 + (size_t)lane * 8);
    }
    short8 bh[4], bl[4];
#pragma unroll
    for (int u = 0; u < 4; ++u) {
      const int row = 16 * u + (lane & 15);
      const unsigned* bp = (const unsigned*)&Bs[row * 70 + s * 32 + (lane >> 4) * 8];
      uint4v hv = {bp[0], bp[1], bp[2], bp[3]};
      bh[u] = __builtin_bit_cast(short8, hv);
      const unsigned* bpl = bp + 2240;
      uint4v lv = {bpl[0], bpl[1], bpl[2], bpl[3]};
      bl[u] = __builtin_bit_cast(short8, lv);
    }
#pragma unroll
    for (int m = 0; m < 2; ++m)
#pragma unroll
      for (int u = 0; u < 4; ++u) {
        f32x4 a = acc[m * 4 + u];
        a = __builtin_amdgcn_mfma_f32_16x16x32_bf16(ah[m], bh[u], a, 0, 0, 0);
        a = __builtin_amdgcn_mfma_f32_16x16x32_bf16(al[m], bh[u], a, 0, 0, 0);
        a = __builtin_amdgcn_mfma_f32_16x16x32_bf16(ah[m], bl[u], a, 0, 0, 0);
        acc[m * 4 + u] = a;
      }
  }
#pragma unroll
  for (int m = 0; m < 2; ++m)
#pragma unroll
    for (int u = 0; u < 4; ++u) {
      const int pn = n0 + u * 16 + (lane & 15);
      const int img2 = pn >> 14;
      const int rem2 = pn & 16383;
#pragma unroll
      for (int r = 0; r < 4; ++r) {
        const int co = (wave + m * 4) * 16 + (lane >> 4) * 4 + r;
        float val = fmaxf(acc[m * 4 + u][r] + bias[co], 0.f);
        out[((size_t)img2 * 128 + co) * 16384 + rem2] = val;
      }
    }
}

// ---- weight packs --------------------------------------------------------
template<bool SPLIT>
__global__ __launch_bounds__(256) void k_pack_o(
    const float* __restrict__ w, unsigned short* __restrict__ p,
    int Co, int Ci, int ntap, int TMT, int E) {
  int i = blockIdx.x * 256 + threadIdx.x;
  if (i >= E) return;
  const int NC = Ci >> 5;
  int j = i & 7, lane = (i >> 3) & 63, r = i >> 9;
  int mt = r % TMT; r /= TMT;
  int sp = 0;
  if (SPLIT) { sp = r % 2; r /= 2; }
  int cic = r % NC; r /= NC;
  int T = r % ntap; int coG = r / ntap;
  int co = coG * (TMT * 16) + mt * 16 + (lane & 15);
  int ci = cic * 32 + (lane >> 4) * 8 + j;
  float wv = w[((size_t)co * Ci + ci) * ntap + T];
  unsigned short hv = f2bf(wv);
  p[i] = (SPLIT && sp == 1) ? f2bf(wv - bf2f(hv)) : hv;
}

__global__ __launch_bounds__(256) void k_pack_ct(
    const float* __restrict__ w, unsigned short* __restrict__ p,
    int Ci, int CoR, int TMT, int E) {
  int i = blockIdx.x * 256 + threadIdx.x;
  if (i >= E) return;
  const int NC = Ci >> 5;
  int j = i & 7, lane = (i >> 3) & 63, r = i >> 9;
  int mt = r % TMT; r /= TMT;
  int cic = r % NC; r /= NC;
  int T = r % 16;   int coG = r / 16;
  int phx = T >> 2, t = T & 3;
  int dy = phx >> 1, dx = phx & 1, ty = t >> 1, tx = t & 1;
  int ky = 2 * ty + 1 - dy, kx = 2 * tx + 1 - dx;
  int co = coG * (TMT * 16) + mt * 16 + (lane & 15);
  int ci = cic * 32 + (lane >> 4) * 8 + j;
  float wv = (co < CoR) ? w[(((size_t)ci * CoR + co) * 4 + ky) * 4 + kx] : 0.f;
  p[i] = f2bf(wv);
}

__global__ __launch_bounds__(256) void k_pack_e1(
    const float* __restrict__ w, unsigned short* __restrict__ p) {
  int i = blockIdx.x * 256 + threadIdx.x;
  int j = i & 7, lane = (i >> 3) & 63, r = i >> 9;
  int mt = r % 8; r /= 8;
  int sp = r % 2; r /= 2;
  int cic = r;
  int co = mt * 16 + (lane & 15);
  int kk = cic * 32 + (lane >> 4) * 8 + j;
  int tap = kk >> 2, c = kk & 3;
  float wv = (c < 3) ? w[(((size_t)co * 3 + c) * 4 + (tap >> 2)) * 4 + (tap & 3)] : 0.f;
  unsigned short hv = f2bf(wv);
  p[i] = (sp == 1) ? f2bf(wv - bf2f(hv)) : hv;
}

// ================= fp32 kernels (tier-3 fallback) =========================
template<int COB, bool RELU_OUT>
__global__ __launch_bounds__(256) void k_conv4(
    const float* __restrict__ in, const float* __restrict__ w,
    const float* __restrict__ bias, float* __restrict__ out,
    int N, int Ci, int Hi, int Wi, int Co) {
  const int Ho = Hi >> 1, Wo = Wi >> 1;
  const int ow = blockIdx.x * 16 + (threadIdx.x & 15);
  const int oh = blockIdx.y * 16 + (threadIdx.x >> 4);
  const int zcnt = Co / COB;
  const int co0 = (blockIdx.z % zcnt) * COB;
  const int n   = blockIdx.z / zcnt;
  if (oh >= Ho || ow >= Wo) return;
  const float* __restrict__ ip = in + (size_t)n * Ci * Hi * Wi;
  float acc[COB];
#pragma unroll
  for (int j = 0; j < COB; ++j) acc[j] = bias[co0 + j];
  const int ih0 = 2 * oh - 1, iw0 = 2 * ow - 1;
  for (int ci = 0; ci < Ci; ++ci) {
    const float* __restrict__ ic = ip + (size_t)ci * Hi * Wi;
    float v[16];
#pragma unroll
    for (int kh = 0; kh < 4; ++kh) {
      const int ih = ih0 + kh;
      const bool hok = (unsigned)ih < (unsigned)Hi;
      const float* __restrict__ irow = ic + (long)ih * Wi;
#pragma unroll
      for (int kw = 0; kw < 4; ++kw) {
        const int iw = iw0 + kw;
        v[kh * 4 + kw] = (hok && (unsigned)iw < (unsigned)Wi) ? irow[iw] : 0.f;
      }
    }
#pragma unroll
    for (int j = 0; j < COB; ++j) {
      const float* __restrict__ wc = w + ((size_t)(co0 + j) * Ci + ci) * 16;
#pragma unroll
      for (int t = 0; t < 16; ++t) acc[j] = fmaf(v[t], wc[t], acc[j]);
    }
  }
#pragma unroll
  for (int j = 0; j < COB; ++j) {
    float a = acc[j];
    if (RELU_OUT) a = fmaxf(a, 0.f);
    out[(((size_t)n * Co + co0 + j) * Ho + oh) * Wo + ow] = a;
  }
}

template<int COB, bool RELU_IN, int CSPLIT>
__global__ __launch_bounds__(256) void k_conv3(
    const float* __restrict__ in, const float* __restrict__ w,
    float* __restrict__ out, int N, int Ci, int H, int W, int Co) {
  const int ow = blockIdx.x * 16 + (threadIdx.x & 15);
  const int oh = blockIdx.y * 16 + (threadIdx.x >> 4);
  const int zcnt = Co / COB;
  const int z = blockIdx.z;
  const int cs  = z % CSPLIT;
  const int co0 = ((z / CSPLIT) % zcnt) * COB;
  const int n   = z / (CSPLIT * zcnt);
  if (oh >= H || ow >= W) return;
  const int CPS = Ci / CSPLIT;
  const float* __restrict__ ip = in + (size_t)n * Ci * H * W;
  float acc[COB];
#pragma unroll
  for (int j = 0; j < COB; ++j) acc[j] = 0.f;
  for (int ci = cs * CPS; ci < (cs + 1) * CPS; ++ci) {
    const float* __restrict__ ic = ip + (size_t)ci * H * W;
    float v[9];
#pragma unroll
    for (int kh = 0; kh < 3; ++kh) {
      const int ih = oh - 1 + kh;
      const bool hok = (unsigned)ih < (unsigned)H;
      const float* __restrict__ irow = ic + (long)ih * W;
#pragma unroll
      for (int kw = 0; kw < 3; ++kw) {
        const int iw = ow - 1 + kw;
        float t = (hok && (unsigned)iw < (unsigned)W) ? irow[iw] : 0.f;
        if (RELU_IN) t = fmaxf(t, 0.f);
        v[kh * 3 + kw] = t;
      }
    }
#pragma unroll
    for (int j = 0; j < COB; ++j) {
      const float* __restrict__ wc = w + ((size_t)(co0 + j) * Ci + ci) * 9;
#pragma unroll
      for (int t = 0; t < 9; ++t) acc[j] = fmaf(v[t], wc[t], acc[j]);
    }
  }
#pragma unroll
  for (int j = 0; j < COB; ++j) {
    size_t oi = (((size_t)n * Co + co0 + j) * H + oh) * W + ow;
    if (CSPLIT > 1) atomicAdd(&out[oi], acc[j]);
    else out[oi] = acc[j];
  }
}

template<int COB, bool RELU_IN, bool ACCUM>
__global__ __launch_bounds__(256) void k_conv1(
    const float* __restrict__ in, const float* __restrict__ w,
    const float* __restrict__ bias, float* __restrict__ out,
    int N, int Ci, int P, int Co) {
  const int p = blockIdx.x * 256 + threadIdx.x;
  const int co0 = blockIdx.y * COB;
  const int n = blockIdx.z;
  if (p >= P) return;
  float acc[COB];
#pragma unroll
  for (int j = 0; j < COB; ++j) acc[j] = bias ? bias[co0 + j] : 0.f;
  const float* __restrict__ ip = in + (size_t)n * Ci * P + p;
#pragma unroll 8
  for (int ci = 0; ci < Ci; ++ci) {
    float v = ip[(size_t)ci * P];
    if (RELU_IN) v = fmaxf(v, 0.f);
#pragma unroll
    for (int j = 0; j < COB; ++j)
      acc[j] = fmaf(v, w[(size_t)(co0 + j) * Ci + ci], acc[j]);
  }
#pragma unroll
  for (int j = 0; j < COB; ++j) {
    size_t oi = ((size_t)n * Co + co0 + j) * P + p;
    if (ACCUM) out[oi] += acc[j]; else out[oi] = acc[j];
  }
}

template<int COB, bool RELU_IN, bool RELU_OUT>
__global__ __launch_bounds__(256) void k_convT(
    const float* __restrict__ in, const float* __restrict__ w,
    const float* __restrict__ bias, float* __restrict__ out,
    int N, int Ci, int Hi, int Wi, int Co) {
  const int Ho = Hi * 2, Wo = Wi * 2;
  const int x = blockIdx.x * 16 + (threadIdx.x & 15);
  const int y = blockIdx.y * 16 + (threadIdx.x >> 4);
  const int zcnt = Co / COB;
  const int co0 = (blockIdx.z % zcnt) * COB;
  const int n   = blockIdx.z / zcnt;
  if (x >= Wi || y >= Hi) return;
  const float* __restrict__ ip = in + (size_t)n * Ci * Hi * Wi;
  float a00[COB], a01[COB], a10[COB], a11[COB];
#pragma unroll
  for (int j = 0; j < COB; ++j) {
    float b = bias[co0 + j];
    a00[j] = b; a01[j] = b; a10[j] = b; a11[j] = b;
  }
  const bool r0 = y > 0, r2 = y + 1 < Hi, c0 = x > 0, c2 = x + 1 < Wi;
#pragma unroll 2
  for (int ci = 0; ci < Ci; ++ci) {
    const float* __restrict__ ic = ip + (size_t)ci * Hi * Wi + (size_t)y * Wi + x;
    float v00 = 0.f, v01 = 0.f, v02 = 0.f, v10 = 0.f, v12 = 0.f,
          v20 = 0.f, v21 = 0.f, v22 = 0.f;
    float v11 = ic[0];
    if (c0) v10 = ic[-1];
    if (c2) v12 = ic[1];
    if (r0) { v01 = ic[-Wi]; if (c0) v00 = ic[-Wi - 1]; if (c2) v02 = ic[-Wi + 1]; }
    if (r2) { v21 = ic[Wi];  if (c0) v20 = ic[Wi - 1];  if (c2) v22 = ic[Wi + 1]; }
    if (RELU_IN) {
      v00 = fmaxf(v00, 0.f); v01 = fmaxf(v01, 0.f); v02 = fmaxf(v02, 0.f);
      v10 = fmaxf(v10, 0.f); v11 = fmaxf(v11, 0.f); v12 = fmaxf(v12, 0.f);
      v20 = fmaxf(v20, 0.f); v21 = fmaxf(v21, 0.f); v22 = fmaxf(v22, 0.f);
    }
#pragma unroll
    for (int j = 0; j < COB; ++j) {
      const float* __restrict__ wc = w + ((size_t)ci * Co + co0 + j) * 16;
      a00[j] = fmaf(v11, wc[5],  fmaf(v10, wc[7],  fmaf(v01, wc[13], fmaf(v00, wc[15], a00[j]))));
      a01[j] = fmaf(v12, wc[4],  fmaf(v11, wc[6],  fmaf(v02, wc[12], fmaf(v01, wc[14], a01[j]))));
      a10[j] = fmaf(v21, wc[1],  fmaf(v20, wc[3],  fmaf(v11, wc[9],  fmaf(v10, wc[11], a10[j]))));
      a11[j] = fmaf(v22, wc[0],  fmaf(v21, wc[2],  fmaf(v12, wc[8],  fmaf(v11, wc[10], a11[j]))));
    }
  }
#pragma unroll
  for (int j = 0; j < COB; ++j) {
    size_t b = ((size_t)n * Co + co0 + j) * Ho;
    float o00 = a00[j], o01 = a01[j], o10 = a10[j], o11 = a11[j];
    if (RELU_OUT) {
      o00 = fmaxf(o00, 0.f); o01 = fmaxf(o01, 0.f);
      o10 = fmaxf(o10, 0.f); o11 = fmaxf(o11, 0.f);
    }
    out[(b + 2 * y) * Wo + 2 * x]         = o00;
    out[(b + 2 * y) * Wo + 2 * x + 1]     = o01;
    out[(b + 2 * y + 1) * Wo + 2 * x]     = o10;
    out[(b + 2 * y + 1) * Wo + 2 * x + 1] = o11;
  }
}

// ---- VQ full-batch (adds prevq bias qb on read) --------------------------
__global__ __launch_bounds__(256, 2) void k_vq(
    const float* __restrict__ ze, const float* __restrict__ emb,
    const float* __restrict__ qb,
    float* __restrict__ zq, float* __restrict__ loss) {
  __shared__ float e2s[512];
  const int tid = threadIdx.x;
  for (int k = tid; k < 512; k += 256) {
    const f32x4* e4 = (const f32x4*)(emb + (size_t)k * 64);
    float s = 0.f;
#pragma unroll
    for (int dq = 0; dq < 16; ++dq) {
      f32x4 ev = e4[dq];
      s = fmaf(ev[0], ev[0], s); s = fmaf(ev[1], ev[1], s);
      s = fmaf(ev[2], ev[2], s); s = fmaf(ev[3], ev[3], s);
    }
    e2s[k] = s;
  }
  __syncthreads();
  const int p = blockIdx.x * 256 + tid;
  const int n = p >> 10, px = p & 1023;
  float xv[64];
  const float* __restrict__ zp = ze + (size_t)n * 64 * 1024 + px;
#pragma unroll
  for (int d = 0; d < 64; ++d) xv[d] = zp[(size_t)d * 1024] + (qb ? qb[d] : 0.f);
  float best = 1e30f; int bi = 0;
  for (int k = 0; k < 512; ++k) {
    const f32x4* e4 = (const f32x4*)(emb + (size_t)k * 64);
    float dot = 0.f;
#pragma unroll
    for (int dq = 0; dq < 16; ++dq) {
      f32x4 ev = e4[dq];
      dot = fmaf(xv[4 * dq],     ev[0], dot);
      dot = fmaf(xv[4 * dq + 1], ev[1], dot);
      dot = fmaf(xv[4 * dq + 2], ev[2], dot);
      dot = fmaf(xv[4 * dq + 3], ev[3], dot);
    }
    float sc = fmaf(-2.f, dot, e2s[k]);
    if (sc < best) { best = sc; bi = k; }
  }
  const float* __restrict__ eb = emb + (size_t)bi * 64;
  float* __restrict__ qp = zq + (size_t)n * 64 * 1024 + px;
  float l = 0.f;
#pragma unroll
  for (int d = 0; d < 64; ++d) {
    float ev = eb[d];
    qp[(size_t)d * 1024] = ev;
    float df = ev - xv[d];
    l = fmaf(df, df, l);
  }
#pragma unroll
  for (int off = 32; off > 0; off >>= 1) l += __shfl_down(l, off, 64);
  if ((tid & 63) == 0) atomicAdd(loss, l * (2.f / 2097152.f));
}

__global__ __launch_bounds__(64) void k_vq64(
    const float* __restrict__ ze, const float* __restrict__ emb,
    float* __restrict__ zq, float* __restrict__ loss,
    int N, int P, int K) {
  const int t = blockIdx.x * 64 + threadIdx.x;
  if (t >= N * P) return;
  const int n = t / P, p = t % P;
  float xv[64];
  const float* __restrict__ zp = ze + (size_t)n * 64 * P + p;
#pragma unroll
  for (int d = 0; d < 64; ++d) xv[d] = zp[(size_t)d * P];
  float best = 1e30f; int bi = 0;
  for (int k = 0; k < K; ++k) {
    const float* __restrict__ e = emb + (size_t)k * 64;
    float dot = 0.f, e2 = 0.f;
#pragma unroll
    for (int d = 0; d < 64; ++d) {
      float ev = e[d];
      dot = fmaf(xv[d], ev, dot);
      e2  = fmaf(ev, ev, e2);
    }
    float score = e2 - 2.f * dot;
    if (score < best) { best = score; bi = k; }
  }
  const float* __restrict__ eb = emb + (size_t)bi * 64;
  float* __restrict__ qp = zq + (size_t)n * 64 * P + p;
  float l = 0.f;
#pragma unroll
  for (int d = 0; d < 64; ++d) {
    float ev = eb[d];
    qp[(size_t)d * P] = ev;
    float df = ev - xv[d];
    l = fmaf(df, df, l);
  }
#pragma unroll
  for (int off = 32; off > 0; off >>= 1) l += __shfl_down(l, off, 64);
  if ((threadIdx.x & 63) == 0) atomicAdd(loss, l * (2.f / 2097152.f));
}

extern "C" void kernel_launch(void* const* d_in, const int* in_sizes, int n_in,
                              void* d_out, int out_size, void* d_ws, size_t ws_size,
                              hipStream_t stream) {
  const float* x    = (const float*)d_in[0];
  const float* ew1  = (const float*)d_in[1];
  const float* eb1  = (const float*)d_in[2];
  const float* ew2  = (const float*)d_in[3];
  const float* eb2  = (const float*)d_in[4];
  const float* ew3  = (const float*)d_in[5];
  const float* eb3  = (const float*)d_in[6];
  const float* erw3 = (const float*)d_in[7];
  const float* erw1 = (const float*)d_in[8];
  const float* pqw  = (const float*)d_in[9];
  const float* pqb  = (const float*)d_in[10];
  const float* emb  = (const float*)d_in[11];
  const float* dw1  = (const float*)d_in[12];
  const float* db1  = (const float*)d_in[13];
  const float* drw3 = (const float*)d_in[14];
  const float* drw1 = (const float*)d_in[15];
  const float* dw2  = (const float*)d_in[16];
  const float* db2  = (const float*)d_in[17];
  const float* dw3  = (const float*)d_in[18];
  const float* db3  = (const float*)d_in[19];
  float* out = (float*)d_out;
  char*  ws  = (char*)d_ws;
  float* loss = out + 6291456;
  const size_t MiB = 1048576ull, KiB = 1024ull;

  dim3 blk(256);
  hipMemsetAsync(loss, 0, 4, stream);

  unsigned syct = 0, sxct = 0;
  for (int T = 0; T < 16; ++T) {
    int phx = T >> 2, dy = phx >> 1, dx = phx & 1, t = T & 3, ty = t >> 1, tx = t & 1;
    int sy = (dy == 0) ? (ty ? -1 : 0) : (ty ? 0 : 1);
    int sx = (dx == 0) ? (tx ? -1 : 0) : (tx ? 0 : 1);
    syct |= (unsigned)(sy + 1) << (2 * T);
    sxct |= (unsigned)(sx + 1) << (2 * T);
  }
  unsigned syc3 = 0, sxc3 = 0;
  for (int t = 0; t < 9; ++t) {
    syc3 |= (unsigned)(t / 3) << (2 * t);
    sxc3 |= (unsigned)(t % 3) << (2 * t);
  }
  unsigned syc4 = 0, sxc4 = 0;
  for (int t = 0; t < 16; ++t) {
    syc4 |= (unsigned)(t / 4) << (2 * t);
    sxc4 |= (unsigned)(t % 4) << (2 * t);
  }
  const unsigned sy1 = 1, sx1 = 1;

  auto packs = [&](char* PB) {
    unsigned short* e2p   = (unsigned short*)(PB);
    unsigned short* e3p   = (unsigned short*)(PB + 2048 * KiB);
    unsigned short* erc3p = (unsigned short*)(PB + 10240 * KiB);
    unsigned short* erc1p = (unsigned short*)(PB + 10816 * KiB);
    unsigned short* pqp   = (unsigned short*)(PB + 10880 * KiB);
    unsigned short* d1p   = (unsigned short*)(PB + 11008 * KiB);
    unsigned short* d2p   = (unsigned short*)(PB + 11520 * KiB);
    unsigned short* dc3p  = (unsigned short*)(PB + 12544 * KiB);
    unsigned short* dc1p  = (unsigned short*)(PB + 12688 * KiB);
    unsigned short* e1p   = (unsigned short*)(PB + 12704 * KiB);
    unsigned short* d3p   = (unsigned short*)(PB + 12832 * KiB);
    k_pack_o<true ><<<dim3(1048576 / 256), blk, 0, stream>>>(ew2,  e2p,  256, 128, 16, 8, 1048576);
    k_pack_o<true ><<<dim3(4194304 / 256), blk, 0, stream>>>(ew3,  e3p,  512, 256, 16, 8, 4194304);
    k_pack_o<true ><<<dim3(294912 / 256),  blk, 0, stream>>>(erw3, erc3p, 32, 512,  9, 2, 294912);
    k_pack_o<true ><<<dim3(32768 / 256),   blk, 0, stream>>>(erw1, erc1p, 512, 32,  1, 8, 32768);
    k_pack_o<true ><<<dim3(65536 / 256),   blk, 0, stream>>>(pqw,  pqp,   64, 512,  1, 4, 65536);
    k_pack_ct<<<dim3(262144 / 256), blk, 0, stream>>>(dw1, d1p, 64, 256, 4, 262144);
    k_pack_ct<<<dim3(524288 / 256), blk, 0, stream>>>(dw2, d2p, 256, 128, 4, 524288);
    k_pack_o<false><<<dim3(73728 / 256),   blk, 0, stream>>>(drw3, dc3p,  32, 256,  9, 2, 73728);
    k_pack_o<false><<<dim3(8192 / 256),    blk, 0, stream>>>(drw1, dc1p, 256, 32,  1, 8, 8192);
    k_pack_e1<<<dim3(256), blk, 0, stream>>>(ew1, e1p);
    k_pack_ct<<<dim3(65536 / 256), blk, 0, stream>>>(dw3, d3p, 128, 3, 2, 65536);
  };

  if (ws_size >= 498ull * MiB) {
    // ============ Tier 1: full batch ============
    float* z1 = (float*)ws;
    float* z2 = (float*)(ws + 256 * MiB);
    float* z3 = (float*)(ws + 384 * MiB);
    float* h  = (float*)(ws + 448 * MiB);
    float* ze = (float*)(ws + 452 * MiB);
    float* zq = (float*)(ws + 460 * MiB);
    float* hd = (float*)(ws + 468 * MiB);
    char*  PB = ws + 484 * MiB;
    unsigned short* e2p   = (unsigned short*)(PB);
    unsigned short* e3p   = (unsigned short*)(PB + 2048 * KiB);
    unsigned short* erc3p = (unsigned short*)(PB + 10240 * KiB);
    unsigned short* erc1p = (unsigned short*)(PB + 10816 * KiB);
    unsigned short* pqp   = (unsigned short*)(PB + 10880 * KiB);
    unsigned short* d1p   = (unsigned short*)(PB + 11008 * KiB);
    unsigned short* d2p   = (unsigned short*)(PB + 11520 * KiB);
    unsigned short* dc3p  = (unsigned short*)(PB + 12544 * KiB);
    unsigned short* dc1p  = (unsigned short*)(PB + 12688 * KiB);
    unsigned short* e1p   = (unsigned short*)(PB + 12704 * KiB);
    unsigned short* d3p   = (unsigned short*)(PB + 12832 * KiB);
    packs(PB);

    // encoder
    k_mfenc1<<<dim3(8192), blk, 0, stream>>>(x, e1p, eb1, z1);
    k_mfconv<4, 2, 2, 1, true, false, true, true, 0><<<dim3(2048, 2), blk, 0, stream>>>(
        z1, e2p, eb2, z2, 128, 128, 128, 6, 12, 256, 16, 16, syc4, sxc4, 64, 4096, 256);
    k_mfconv<4, 2, 2, 1, true, false, false, true, 0><<<dim3(512, 4), blk, 0, stream>>>(
        z2, e3p, eb3, z3, 256, 64, 64, 5, 10, 512, 16, 16, syc4, sxc4, 32, 1024, 512);
    // res stack + prevq + VQ
    for (int i = 0; i < 2; ++i) {
      k_mfhalo<2, 0, true, true, false, false><<<dim3(512, 1), blk, 0, stream>>>(
          z3, erc3p, nullptr, h, 512, 32, 32, 5, 10, 32, 9, syc3, sxc3, 32);
      k_mfconv<4, 2, 0, 1, true, true, false, false, 1><<<dim3(512, 4), blk, 0, stream>>>(
          h, erc1p, nullptr, z3, 32, 32, 32, 5, 10, 512, 1, 1, sy1, sx1, 32, 1024, 512);
    }
    hipMemsetAsync(ze, 0, 8 * MiB, stream);
    k_mfconv<4, 1, 0, 4, true, true, false, false, 2><<<dim3(512, 1, 4), blk, 0, stream>>>(
        z3, pqp, nullptr, ze, 512, 32, 32, 5, 10, 64, 1, 1, sy1, sx1, 32, 1024, 64);
    k_vq<<<dim3(128), blk, 0, stream>>>(ze, emb, pqb, zq, loss);
    // decoder
    float* y1 = (float*)(ws + 256 * MiB);
    float* y2 = (float*)ws;
    k_mfhalo<4, 1, false, false, false, true><<<dim3(512, 4), blk, 0, stream>>>(
        zq, d1p, db1, y1, 64, 32, 32, 5, 10, 256, 16, syct, sxct, 256);
    for (int i = 0; i < 2; ++i) {
      k_mfhalo<2, 0, false, true, false, false><<<dim3(2048, 1), blk, 0, stream>>>(
          y1, dc3p, nullptr, hd, 256, 64, 64, 6, 12, 32, 9, syc3, sxc3, 32);
      k_mfconv<4, 2, 0, 1, false, true, false, false, 1><<<dim3(2048, 2), blk, 0, stream>>>(
          hd, dc1p, nullptr, y1, 32, 64, 64, 6, 12, 256, 1, 1, sy1, sx1, 64, 4096, 256);
    }
    k_mfhalo<4, 1, false, true, true, true><<<dim3(2048, 2), blk, 0, stream>>>(
        y1, d2p, db2, y2, 256, 64, 64, 6, 12, 128, 16, syct, sxct, 128);
    k_mfhalo<2, 1, false, false, false, true><<<dim3(8192, 1), blk, 0, stream>>>(
        y2, d3p, db3, out, 128, 128, 128, 7, 14, 3, 16, syct, sxct, 3);
    return;
  }

  if (ws_size >= 128ull * MiB) {
    // ============ Tier 2: chunked ============
    float* z3  = (float*)ws;
    float* h   = (float*)(ws + 64 * MiB);
    float* ze  = (float*)(ws + 68 * MiB);
    float* zq  = (float*)(ws + 100 * MiB);
    char*  PB  = ws + 115 * MiB;
    unsigned short* e2p   = (unsigned short*)(PB);
    unsigned short* e3p   = (unsigned short*)(PB + 2048 * KiB);
    unsigned short* erc3p = (unsigned short*)(PB + 10240 * KiB);
    unsigned short* erc1p = (unsigned short*)(PB + 10816 * KiB);
    unsigned short* pqp   = (unsigned short*)(PB + 10880 * KiB);
    unsigned short* d1p   = (unsigned short*)(PB + 11008 * KiB);
    unsigned short* d2p   = (unsigned short*)(PB + 11520 * KiB);
    unsigned short* dc3p  = (unsigned short*)(PB + 12544 * KiB);
    unsigned short* dc1p  = (unsigned short*)(PB + 12688 * KiB);
    unsigned short* e1p   = (unsigned short*)(PB + 12704 * KiB);
    unsigned short* d3p   = (unsigned short*)(PB + 12832 * KiB);
    packs(PB);

    const int NE = 4;
    float* z1c = (float*)(ws + 64 * MiB);
    float* z2c = (float*)(ws + 96 * MiB);
    for (int n0 = 0; n0 < 32; n0 += NE) {
      const float* xb = x + (size_t)n0 * 3 * 65536;
      float* z3b = z3 + (size_t)n0 * 512 * 1024;
      k_mfenc1<<<dim3(NE * 256), blk, 0, stream>>>(xb, e1p, eb1, z1c);
      k_mfconv<4, 2, 2, 1, true, false, true, true, 0><<<dim3(256, 2), blk, 0, stream>>>(
          z1c, e2p, eb2, z2c, 128, 128, 128, 6, 12, 256, 16, 16, syc4, sxc4, 64, 4096, 256);
      k_mfconv<4, 2, 2, 1, true, false, false, true, 0><<<dim3(64, 4), blk, 0, stream>>>(
          z2c, e3p, eb3, z3b, 256, 64, 64, 5, 10, 512, 16, 16, syc4, sxc4, 32, 1024, 512);
    }
    for (int i = 0; i < 2; ++i) {
      k_mfhalo<2, 0, true, true, false, false><<<dim3(512, 1), blk, 0, stream>>>(
          z3, erc3p, nullptr, h, 512, 32, 32, 5, 10, 32, 9, syc3, sxc3, 32);
      k_mfconv<4, 2, 0, 1, true, true, false, false, 1><<<dim3(512, 4), blk, 0, stream>>>(
          h, erc1p, nullptr, z3, 32, 32, 32, 5, 10, 512, 1, 1, sy1, sx1, 32, 1024, 512);
    }
    hipMemsetAsync(ze, 0, 8 * MiB, stream);
    k_mfconv<4, 1, 0, 4, true, true, false, false, 2><<<dim3(512, 1, 4), blk, 0, stream>>>(
        z3, pqp, nullptr, ze, 512, 32, 32, 5, 10, 64, 1, 1, sy1, sx1, 32, 1024, 64);
    k_vq<<<dim3(128), blk, 0, stream>>>(ze, emb, pqb, zq, loss);

    const int ND = 8;
    float* y1c = (float*)ws;
    float* hd  = (float*)(ws + 32 * MiB);
    float* y2c = (float*)(ws + 36 * MiB);
    for (int c = 0; c < 32; c += ND) {
      const float* zqb = zq + (size_t)c * 64 * 1024;
      float* outb = out + (size_t)c * 3 * 65536;
      k_mfhalo<4, 1, false, false, false, true><<<dim3(128, 4), blk, 0, stream>>>(
          zqb, d1p, db1, y1c, 64, 32, 32, 5, 10, 256, 16, syct, sxct, 256);
      for (int i = 0; i < 2; ++i) {
        k_mfhalo<2, 0, false, true, false, false><<<dim3(512, 1), blk, 0, stream>>>(
            y1c, dc3p, nullptr, hd, 256, 64, 64, 6, 12, 32, 9, syc3, sxc3, 32);
        k_mfconv<4, 2, 0, 1, false, true, false, false, 1><<<dim3(512, 2), blk, 0, stream>>>(
            hd, dc1p, nullptr, y1c, 32, 64, 64, 6, 12, 256, 1, 1, sy1, sx1, 64, 4096, 256);
      }
      k_mfhalo<4, 1, false, true, true, true><<<dim3(512, 2), blk, 0, stream>>>(
          y1c, d2p, db2, y2c, 256, 64, 64, 6, 12, 128, 16, syct, sxct, 128);
      k_mfhalo<2, 1, false, false, false, true><<<dim3(2048, 1), blk, 0, stream>>>(
          y2c, d3p, db3, outb, 128, 128, 128, 7, 14, 3, 16, syct, sxct, 3);
    }
    return;
  }

  // ============ Tier 3 fallback (fp32) ============
  const size_t PER_IMG = 12582912ull;
  int NB = (int)(ws_size / PER_IMG);
  if (NB > 32) NB = 32;
  if (NB < 1)  NB = 1;

  for (int n0 = 0; n0 < 32; n0 += NB) {
    const int nb = (32 - n0 < NB) ? (32 - n0) : NB;
    const float* xb   = x   + (size_t)n0 * 3 * 65536;
    float*       outb = out + (size_t)n0 * 3 * 65536;

    float* z1 = (float*)ws;
    float* z2 = (float*)(ws + (size_t)NB * 8388608ull);
    float* z3 = (float*)ws;
    char*  tb = ws + (size_t)NB * 2097152ull;
    float* he = (float*)tb;
    float* ze = (float*)(tb + (size_t)NB * 131072ull);
    float* zq = (float*)(tb + (size_t)NB * 393216ull);
    float* hd = (float*)(tb + (size_t)NB * 655360ull);
    float* y1 = z2;
    float* y2 = (float*)ws;

    k_conv4<4, true ><<<dim3(8, 8, nb * 32), blk, 0, stream>>>(xb, ew1, eb1, z1, nb,   3, 256, 256, 128);
    k_conv4<4, true ><<<dim3(4, 4, nb * 64), blk, 0, stream>>>(z1, ew2, eb2, z2, nb, 128, 128, 128, 256);
    k_conv4<4, false><<<dim3(2, 2, nb * 128), blk, 0, stream>>>(z2, ew3, eb3, z3, nb, 256,  64,  64, 512);
    for (int i = 0; i < 2; ++i) {
      k_conv3<4, true, 1><<<dim3(2, 2, nb * 8), blk, 0, stream>>>(z3, erw3, he, nb, 512, 32, 32, 32);
      k_conv1<8, true, true><<<dim3(4, 64, nb), blk, 0, stream>>>(he, erw1, nullptr, z3, nb, 32, 1024, 512);
    }
    k_conv1<8, true, false><<<dim3(4, 8, nb), blk, 0, stream>>>(z3, pqw, pqb, ze, nb, 512, 1024, 64);
    k_vq64<<<dim3(nb * 16), dim3(64), 0, stream>>>(ze, emb, zq, loss, nb, 1024, 512);
    k_convT<4, false, false><<<dim3(2, 2, nb * 64), blk, 0, stream>>>(zq, dw1, db1, y1, nb,  64, 32, 32, 256);
    for (int i = 0; i < 2; ++i) {
      k_conv3<4, true, 1><<<dim3(4, 4, nb * 8), blk, 0, stream>>>(y1, drw3, hd, nb, 256, 64, 64, 32);
      k_conv1<8, true, true><<<dim3(16, 32, nb), blk, 0, stream>>>(hd, drw1, nullptr, y1, nb, 32, 4096, 256);
    }
    k_convT<4, true, true ><<<dim3(4, 4, nb * 32), blk, 0, stream>>>(y1, dw2, db2, y2, nb, 256, 64, 64, 128);
    k_convT<1, false, false><<<dim3(8, 8, nb * 3), blk, 0, stream>>>(y2, dw3, db3, outb, nb, 128, 128, 128, 3);
  }
}

// Round 11
// 4128.144 us; speedup vs baseline: 1.0321x; 1.0321x over previous
//
#include <hip/hip_runtime.h>
#include <hip/hip_bf16.h>

typedef __attribute__((ext_vector_type(8))) short short8;
typedef __attribute__((ext_vector_type(4))) float f32x4;
typedef __attribute__((ext_vector_type(4))) unsigned int uint4v;

__device__ __forceinline__ unsigned short f2bf(float f) {
  unsigned u = __builtin_bit_cast(unsigned, f);
  u = (u + 0x7FFFu + ((u >> 16) & 1u)) >> 16;
  return (unsigned short)u;
}
__device__ __forceinline__ float bf2f(unsigned short h) {
  unsigned u = ((unsigned)h) << 16;
  return __builtin_bit_cast(float, u);
}
__device__ __forceinline__ unsigned pk_bf16(float a, float b) {
  __hip_bfloat162 h = __float22bfloat162_rn(make_float2(a, b));
  unsigned u;
  __builtin_memcpy(&u, &h, 4);
  return u;
}

// ================= MFMA tap-GEMM conv engine (R8, proven) =================
// M = TMT*MT*16 couts/block, N = 64 p-space px/block, K double-buffered
// 64-ci chunks, 1 sync/chunk. MODE: 0 stride-1; 1 convT x2-up (phases in
// grid.z); 2 stride-2 down. ZSP>1 (MODE!=1): split (tap,chunk) space over
// grid.z with atomics. SPLIT: hi/lo bf16 x3 MFMAs ~ fp32-grade.
// SM: 0 store, 1 +=, 2 atomicAdd. Epilogue masked to co < CoSt.
template<int TMT, int MT, int MODE, int ZSP, bool SPLIT, bool RELU_IN, bool RELU_OUT, bool BIAS, int SM>
__global__ __launch_bounds__(256, 4) void k_mfconv(
    const float* __restrict__ in, const unsigned short* __restrict__ wp,
    const float* __restrict__ bias, float* __restrict__ out,
    int Ci, int inW, int inH, int pWSH, int pHWSH,
    int Co, int ntap, int ntt,
    unsigned syp, unsigned sxp,
    int outW, int outHW, int CoSt) {
  const int tid  = threadIdx.x;
  const int lane = tid & 63, wave = tid >> 6;
  const int pW  = 1 << pWSH;
  const int pHW = 1 << pHWSH;
  const int inHW = inW * inH;
  const int nk32 = Ci >> 5;
  const int KS   = (nk32 >= 2) ? 2 : 1;
  const int NITS = 4 * KS;
  const int cpt  = nk32 / KS;
  const int total = ntap * cpt;
  constexpr int TT = TMT * MT;

  int bx = blockIdx.x;
  const int gx = gridDim.x;
  if ((gx & 7) == 0) bx = (bx & 7) * (gx >> 3) + (bx >> 3);
  const int n0  = bx * 64;
  const int coG = blockIdx.y;
  const int ph  = (MODE == 1) ? blockIdx.z : 0;
  const int tap0 = (MODE == 1) ? ph * 4 : 0;
  const int pdy = ph >> 1, pdx = ph & 1;

  int it0 = 0, itEnd = total;
  if (MODE != 1 && ZSP > 1) {
    const int per = total / ZSP;
    it0 = blockIdx.z * per;
    itEnd = it0 + per;
  }

  constexpr int NPL = SPLIT ? 2 : 1;
  constexpr int PL = 64 * 70;
  __shared__ __align__(16) unsigned short Bs[2 * NPL * PL];

  const int px  = lane;
  const int p   = n0 + px;
  const int img = p >> pHWSH;
  const int rem = p & (pHW - 1);
  const int y   = rem >> pWSH;
  const int x   = rem & (pW - 1);
  const size_t base_img = (size_t)img * Ci * inHW;

  constexpr int NTO = (TMT == 4) ? 4 : 2;
  const int mt0 = (TMT == 4) ? wave : (wave & 1);
  const int ntb = (TMT == 4) ? 0 : ((wave >> 1) * 2);
  f32x4 acc[MT * NTO];
#pragma unroll
  for (int u = 0; u < MT * NTO; ++u) acc[u] = (f32x4){0.f, 0.f, 0.f, 0.f};

  const int cp = wave;
  float v[16];

  auto ldr = [&](int tap_, int chunk_) {
    const int T = tap0 + tap_;
    const int dy = (int)((syp >> (2 * T)) & 3u) - 1;
    const int dx = (int)((sxp >> (2 * T)) & 3u) - 1;
    const int ys = (MODE == 2) ? (2 * y + dy) : (y + dy);
    const int xs = (MODE == 2) ? (2 * x + dx) : (x + dx);
    const bool ok = ((unsigned)ys < (unsigned)inH) && ((unsigned)xs < (unsigned)inW);
    const float* __restrict__ ipb = in + base_img + (ptrdiff_t)ys * inW + xs;
    const int ci0 = chunk_ * (KS * 32);
#pragma unroll
    for (int it2 = 0; it2 < 8; ++it2) {
      if (it2 >= NITS) break;
      const int cl = 2 * (cp + 4 * it2);
      float a = 0.f, b = 0.f;
      if (ok) {
        a = ipb[(size_t)(ci0 + cl) * inHW];
        b = ipb[(size_t)(ci0 + cl + 1) * inHW];
      }
      if (RELU_IN) { a = fmaxf(a, 0.f); b = fmaxf(b, 0.f); }
      v[2 * it2] = a; v[2 * it2 + 1] = b;
    }
  };
  auto pwr = [&](int b) {
#pragma unroll
    for (int it2 = 0; it2 < 8; ++it2) {
      if (it2 >= NITS) break;
      const int cl = 2 * (cp + 4 * it2);
      float a = v[2 * it2], c = v[2 * it2 + 1];
      unsigned hp = pk_bf16(a, c);
      *(unsigned*)&Bs[(b * NPL) * PL + px * 70 + cl] = hp;
      if (SPLIT) {
        float h0 = bf2f((unsigned short)hp), h1 = bf2f((unsigned short)(hp >> 16));
        *(unsigned*)&Bs[(b * NPL + 1) * PL + px * 70 + cl] = pk_bf16(a - h0, c - h1);
      }
    }
  };

  int tap = it0 / cpt, chunk = it0 % cpt;
  ldr(tap, chunk);
  pwr(0);
  __syncthreads();

  for (int it = it0; it < itEnd; ++it) {
    const int b = (it - it0) & 1;
    const int T = tap0 + tap;
    int tap2 = tap, chunk2 = chunk + 1;
    if (chunk2 == cpt) { chunk2 = 0; tap2 = tap + 1; }
    const bool more = (it + 1 < itEnd);
    if (more) ldr(tap2, chunk2);
#pragma unroll
    for (int s = 0; s < 2; ++s) {
      if (s >= KS) break;
      const int cic = chunk * KS + s;
      short8 ah[MT], al[MT];
#pragma unroll
      for (int m = 0; m < MT; ++m) {
        const int mtm = mt0 + m * TMT;
        size_t abase;
        if (SPLIT) abase = ((((size_t)coG * ntt + T) * nk32 + cic) * 2 * TT + mtm) * 512;
        else       abase = ((((size_t)coG * ntt + T) * nk32 + cic) * TT + mtm) * 512;
        ah[m] = *(const short8*)(wp + abase + (size_t)lane * 8);
        if (SPLIT) al[m] = *(const short8*)(wp + abase + (size_t)TT * 512 + (size_t)lane * 8);
      }
      short8 bh[NTO], bl[NTO];
#pragma unroll
      for (int u = 0; u < NTO; ++u) {
        const int row = 16 * (ntb + u) + (lane & 15);
        const unsigned* bp = (const unsigned*)&Bs[(b * NPL) * PL + row * 70 + s * 32 + (lane >> 4) * 8];
        uint4v hv = {bp[0], bp[1], bp[2], bp[3]};
        bh[u] = __builtin_bit_cast(short8, hv);
        if (SPLIT) {
          const unsigned* bpl = bp + (PL >> 1);
          uint4v lv = {bpl[0], bpl[1], bpl[2], bpl[3]};
          bl[u] = __builtin_bit_cast(short8, lv);
        }
      }
#pragma unroll
      for (int m = 0; m < MT; ++m)
#pragma unroll
        for (int u = 0; u < NTO; ++u) {
          f32x4 a = acc[m * NTO + u];
          a = __builtin_amdgcn_mfma_f32_16x16x32_bf16(ah[m], bh[u], a, 0, 0, 0);
          if (SPLIT) {
            a = __builtin_amdgcn_mfma_f32_16x16x32_bf16(al[m], bh[u], a, 0, 0, 0);
            a = __builtin_amdgcn_mfma_f32_16x16x32_bf16(ah[m], bl[u], a, 0, 0, 0);
          }
          acc[m * NTO + u] = a;
        }
    }
    if (more) {
      pwr(b ^ 1);
      __syncthreads();
    }
    tap = tap2; chunk = chunk2;
  }

  // epilogue: D col=lane&15 (pixel), row=4*(lane>>4)+r (co)
#pragma unroll
  for (int m = 0; m < MT; ++m) {
    const int mtm = mt0 + m * TMT;
#pragma unroll
    for (int u = 0; u < NTO; ++u) {
      const int nt = ntb + u;
      const int pn = n0 + nt * 16 + (lane & 15);
      const int img2 = pn >> pHWSH;
      const int rem2 = pn & (pHW - 1);
      const int y2 = rem2 >> pWSH, x2 = rem2 & (pW - 1);
      int oy, ox;
      if (MODE == 1) { oy = 2 * y2 + pdy; ox = 2 * x2 + pdx; }
      else           { oy = y2;           ox = x2; }
#pragma unroll
      for (int r = 0; r < 4; ++r) {
        const int co = coG * (TT * 16) + mtm * 16 + (lane >> 4) * 4 + r;
        if (co < CoSt) {
          float val = acc[m * NTO + u][r];
          if (BIAS) val += bias[co];
          if (RELU_OUT) val = fmaxf(val, 0.f);
          size_t oi = ((size_t)img2 * Co + co) * outHW + (size_t)oy * outW + ox;
          if (SM == 0) out[oi] = val;
          else if (SM == 1) out[oi] += val;
          else atomicAdd(&out[oi], val);
        }
      }
    }
  }
}

// ================= fused residual layer ===================================
// znew = x + w1 . relu( conv3(relu(x), w3) )   [C -> 32 -> C, HxW square]
// Phase 1: tap-GEMM conv3 with TMT=2 => block computes ALL 32 mid-channels
// for its 64 px. h -> LDS (bf16 hi[/lo]). Phase 2: conv1 K=32 from LDS,
// B frags read once, reused over all m-groups; epilogue adds x (no alias:
// separate znew buffer).
template<int MGRP, bool SPLIT>    // MGRP = C/64: enc 8, dec 4
__global__ __launch_bounds__(256, SPLIT ? 3 : 4) void k_mfres(
    const float* __restrict__ in, const unsigned short* __restrict__ w3p,
    const unsigned short* __restrict__ w1p, float* __restrict__ znew,
    int pWSH, int pHWSH, unsigned syp, unsigned sxp) {
  constexpr int C = MGRP * 64;
  const int tid = threadIdx.x, lane = tid & 63, wave = tid >> 6;
  const int pW = 1 << pWSH, pHW = 1 << pHWSH;
  const int inW = pW, inH = pHW >> pWSH;
  const int inHW = pHW;
  const int nk32 = C >> 5;
  const int cpt = nk32 >> 1;         // KS = 2
  const int total = 9 * cpt;

  int bx = blockIdx.x;
  const int gx = gridDim.x;
  if ((gx & 7) == 0) bx = (bx & 7) * (gx >> 3) + (bx >> 3);
  const int n0 = bx * 64;

  constexpr int NPL = SPLIT ? 2 : 1;
  constexpr int PL = 64 * 70;
  __shared__ __align__(16) unsigned short Bs[2 * NPL * PL];
  __shared__ __align__(16) unsigned short Hs2[NPL * 2560];   // [pl][px][40]

  const int px = lane;
  const int p = n0 + px;
  const int img = p >> pHWSH;
  const int rem = p & (pHW - 1);
  const int y = rem >> pWSH, x = rem & (pW - 1);
  const size_t base_img = (size_t)img * C * inHW;
  const int mt = wave & 1, ntb = (wave >> 1) * 2;
  const int cp = wave;
  float v[16];
  f32x4 acc[2];
  acc[0] = (f32x4){0.f, 0.f, 0.f, 0.f};
  acc[1] = (f32x4){0.f, 0.f, 0.f, 0.f};

  auto ldr = [&](int T, int chunk_) {
    const int dy = (int)((syp >> (2 * T)) & 3u) - 1;
    const int dx = (int)((sxp >> (2 * T)) & 3u) - 1;
    const int ys = y + dy, xs = x + dx;
    const bool ok = ((unsigned)ys < (unsigned)inH) && ((unsigned)xs < (unsigned)inW);
    const float* __restrict__ ipb = in + base_img + (ptrdiff_t)ys * inW + xs;
    const int ci0 = chunk_ * 64;
#pragma unroll
    for (int i2 = 0; i2 < 8; ++i2) {
      const int cl = 2 * (cp + 4 * i2);
      float a = 0.f, b = 0.f;
      if (ok) {
        a = ipb[(size_t)(ci0 + cl) * inHW];
        b = ipb[(size_t)(ci0 + cl + 1) * inHW];
      }
      a = fmaxf(a, 0.f); b = fmaxf(b, 0.f);
      v[2 * i2] = a; v[2 * i2 + 1] = b;
    }
  };
  auto pwr = [&](int b) {
#pragma unroll
    for (int i2 = 0; i2 < 8; ++i2) {
      const int cl = 2 * (cp + 4 * i2);
      float a = v[2 * i2], c = v[2 * i2 + 1];
      unsigned hp = pk_bf16(a, c);
      *(unsigned*)&Bs[(b * NPL) * PL + px * 70 + cl] = hp;
      if (SPLIT) {
        float h0 = bf2f((unsigned short)hp), h1 = bf2f((unsigned short)(hp >> 16));
        *(unsigned*)&Bs[(b * NPL + 1) * PL + px * 70 + cl] = pk_bf16(a - h0, c - h1);
      }
    }
  };

  // ---- phase 1: conv3 C -> 32 ----
  int tap = 0, chunk = 0;
  ldr(0, 0);
  pwr(0);
  __syncthreads();
  for (int it = 0; it < total; ++it) {
    const int b = it & 1;
    const int T = tap;
    int tap2 = tap, chunk2 = chunk + 1;
    if (chunk2 == cpt) { chunk2 = 0; tap2 = tap + 1; }
    const bool more = (it + 1 < total);
    if (more) ldr(tap2, chunk2);
#pragma unroll
    for (int s = 0; s < 2; ++s) {
      const int cic = chunk * 2 + s;
      size_t abase;
      if (SPLIT) abase = (((size_t)T * nk32 + cic) * 2 * 2 + mt) * 512;
      else       abase = (((size_t)T * nk32 + cic) * 2 + mt) * 512;
      short8 ah = *(const short8*)(w3p + abase + (size_t)lane * 8);
      short8 al;
      if (SPLIT) al = *(const short8*)(w3p + abase + 2 * 512 + (size_t)lane * 8);
#pragma unroll
      for (int u = 0; u < 2; ++u) {
        const int row = 16 * (ntb + u) + (lane & 15);
        const unsigned* bp = (const unsigned*)&Bs[(b * NPL) * PL + row * 70 + s * 32 + (lane >> 4) * 8];
        uint4v hv = {bp[0], bp[1], bp[2], bp[3]};
        short8 bh = __builtin_bit_cast(short8, hv);
        f32x4 a = acc[u];
        a = __builtin_amdgcn_mfma_f32_16x16x32_bf16(ah, bh, a, 0, 0, 0);
        if (SPLIT) {
          const unsigned* bpl = bp + (PL >> 1);
          uint4v lv = {bpl[0], bpl[1], bpl[2], bpl[3]};
          short8 bl = __builtin_bit_cast(short8, lv);
          a = __builtin_amdgcn_mfma_f32_16x16x32_bf16(al, bh, a, 0, 0, 0);
          a = __builtin_amdgcn_mfma_f32_16x16x32_bf16(ah, bl, a, 0, 0, 0);
        }
        acc[u] = a;
      }
    }
    if (more) {
      pwr(b ^ 1);
      __syncthreads();
    }
    tap = tap2; chunk = chunk2;
  }

  // ---- h -> LDS (relu, bf16 hi[/lo]) ----
#pragma unroll
  for (int u = 0; u < 2; ++u) {
    const int pxl = (ntb + u) * 16 + (lane & 15);
#pragma unroll
    for (int r = 0; r < 4; ++r) {
      const int co = mt * 16 + (lane >> 4) * 4 + r;
      float val = fmaxf(acc[u][r], 0.f);
      unsigned short hv = f2bf(val);
      Hs2[pxl * 40 + co] = hv;
      if (SPLIT) Hs2[2560 + pxl * 40 + co] = f2bf(val - bf2f(hv));
    }
  }
  __syncthreads();

  // ---- phase 2: conv1 32 -> C, add x ----
  short8 bh2[4], bl2[4];
#pragma unroll
  for (int u = 0; u < 4; ++u) {
    const int row = 16 * u + (lane & 15);
    bh2[u] = *(const short8*)&Hs2[row * 40 + (lane >> 4) * 8];
    if (SPLIT) bl2[u] = *(const short8*)&Hs2[2560 + row * 40 + (lane >> 4) * 8];
  }
#pragma unroll
  for (int g = 0; g < MGRP; ++g) {
    const int mt2 = wave + 4 * g;
    short8 a1h = *(const short8*)(w1p + (size_t)mt2 * 512 + (size_t)lane * 8);
    short8 a1l;
    if (SPLIT) a1l = *(const short8*)(w1p + ((size_t)(MGRP * 4) + mt2) * 512 + (size_t)lane * 8);
    f32x4 a2[4];
#pragma unroll
    for (int u = 0; u < 4; ++u) a2[u] = (f32x4){0.f, 0.f, 0.f, 0.f};
#pragma unroll
    for (int u = 0; u < 4; ++u) {
      a2[u] = __builtin_amdgcn_mfma_f32_16x16x32_bf16(a1h, bh2[u], a2[u], 0, 0, 0);
      if (SPLIT) {
        a2[u] = __builtin_amdgcn_mfma_f32_16x16x32_bf16(a1l, bh2[u], a2[u], 0, 0, 0);
        a2[u] = __builtin_amdgcn_mfma_f32_16x16x32_bf16(a1h, bl2[u], a2[u], 0, 0, 0);
      }
    }
#pragma unroll
    for (int u = 0; u < 4; ++u) {
      const int pn = n0 + u * 16 + (lane & 15);
      const int rem2 = pn & (pHW - 1);
#pragma unroll
      for (int r = 0; r < 4; ++r) {
        const int co = mt2 * 16 + (lane >> 4) * 4 + r;
        size_t oi = ((size_t)img * C + co) * inHW + rem2;
        znew[oi] = in[oi] + a2[u][r];
      }
    }
  }
}

// ================= enc1 as MFMA ===========================================
__global__ __launch_bounds__(256, 4) void k_mfenc1(
    const float* __restrict__ in, const unsigned short* __restrict__ wp,
    const float* __restrict__ bias, float* __restrict__ out) {
  const int tid = threadIdx.x, lane = tid & 63, wave = tid >> 6;
  int bx = blockIdx.x;
  const int gx = gridDim.x;
  if ((gx & 7) == 0) bx = (bx & 7) * (gx >> 3) + (bx >> 3);
  const int n0 = bx * 64;
  const int p = n0 + lane;
  const int img = p >> 14;
  const int rem = p & 16383;
  const int y = rem >> 7, x = rem & 127;
  __shared__ __align__(16) unsigned short Bs[2 * 4480];
  const float* __restrict__ ib = in + (size_t)img * 3 * 65536;
#pragma unroll
  for (int i = 0; i < 8; ++i) {
    const int kk0 = 2 * (wave + 4 * i);
    float vv[2];
#pragma unroll
    for (int q = 0; q < 2; ++q) {
      const int kk = kk0 + q;
      const int tap = kk >> 2, c = kk & 3;
      const int iy = 2 * y + (tap >> 2) - 1, ix = 2 * x + (tap & 3) - 1;
      const bool ok = (c < 3) && ((unsigned)iy < 256u) && ((unsigned)ix < 256u);
      vv[q] = ok ? ib[((size_t)c << 16) + (size_t)iy * 256 + ix] : 0.f;
    }
    unsigned hp = pk_bf16(vv[0], vv[1]);
    *(unsigned*)&Bs[lane * 70 + kk0] = hp;
    float h0 = bf2f((unsigned short)hp), h1 = bf2f((unsigned short)(hp >> 16));
    *(unsigned*)&Bs[4480 + lane * 70 + kk0] = pk_bf16(vv[0] - h0, vv[1] - h1);
  }
  __syncthreads();

  f32x4 acc[8];
#pragma unroll
  for (int u = 0; u < 8; ++u) acc[u] = (f32x4){0.f, 0.f, 0.f, 0.f};
#pragma unroll
  for (int s = 0; s < 2; ++s) {
    short8 ah[2], al[2];
#pragma unroll
    for (int m = 0; m < 2; ++m) {
      const int mtm = wave + m * 4;
      size_t abase = (((size_t)s * 2 + 0) * 8 + mtm) * 512;
      ah[m] = *(const short8*)(wp + abase + (size_t)lane * 8);
      al[m] = *(const short8*)(wp + abase + 8 * 512 + (size_t)lane * 8);
    }
    short8 bh[4], bl[4];
#pragma unroll
    for (int u = 0; u < 4; ++u) {
      const int row = 16 * u + (lane & 15);
      const unsigned* bp = (const unsigned*)&Bs[row * 70 + s * 32 + (lane >> 4) * 8];
      uint4v hv = {bp[0], bp[1], bp[2], bp[3]};
      bh[u] = __builtin_bit_cast(short8, hv);
      const unsigned* bpl = bp + 2240;
      uint4v lv = {bpl[0], bpl[1], bpl[2], bpl[3]};
      bl[u] = __builtin_bit_cast(short8, lv);
    }
#pragma unroll
    for (int m = 0; m < 2; ++m)
#pragma unroll
      for (int u = 0; u < 4; ++u) {
        f32x4 a = acc[m * 4 + u];
        a = __builtin_amdgcn_mfma_f32_16x16x32_bf16(ah[m], bh[u], a, 0, 0, 0);
        a = __builtin_amdgcn_mfma_f32_16x16x32_bf16(al[m], bh[u], a, 0, 0, 0);
        a = __builtin_amdgcn_mfma_f32_16x16x32_bf16(ah[m], bl[u], a, 0, 0, 0);
        acc[m * 4 + u] = a;
      }
  }
#pragma unroll
  for (int m = 0; m < 2; ++m)
#pragma unroll
    for (int u = 0; u < 4; ++u) {
      const int pn = n0 + u * 16 + (lane & 15);
      const int img2 = pn >> 14;
      const int rem2 = pn & 16383;
#pragma unroll
      for (int r = 0; r < 4; ++r) {
        const int co = (wave + m * 4) * 16 + (lane >> 4) * 4 + r;
        float val = fmaxf(acc[m * 4 + u][r] + bias[co], 0.f);
        out[((size_t)img2 * 128 + co) * 16384 + rem2] = val;
      }
    }
}

// ---- weight packs --------------------------------------------------------
template<bool SPLIT>
__global__ __launch_bounds__(256) void k_pack_o(
    const float* __restrict__ w, unsigned short* __restrict__ p,
    int Co, int Ci, int ntap, int TMT, int E) {
  int i = blockIdx.x * 256 + threadIdx.x;
  if (i >= E) return;
  const int NC = Ci >> 5;
  int j = i & 7, lane = (i >> 3) & 63, r = i >> 9;
  int mt = r % TMT; r /= TMT;
  int sp = 0;
  if (SPLIT) { sp = r % 2; r /= 2; }
  int cic = r % NC; r /= NC;
  int T = r % ntap; int coG = r / ntap;
  int co = coG * (TMT * 16) + mt * 16 + (lane & 15);
  int ci = cic * 32 + (lane >> 4) * 8 + j;
  float wv = w[((size_t)co * Ci + ci) * ntap + T];
  unsigned short hv = f2bf(wv);
  p[i] = (SPLIT && sp == 1) ? f2bf(wv - bf2f(hv)) : hv;
}

__global__ __launch_bounds__(256) void k_pack_ct(
    const float* __restrict__ w, unsigned short* __restrict__ p,
    int Ci, int CoR, int TMT, int E) {
  int i = blockIdx.x * 256 + threadIdx.x;
  if (i >= E) return;
  const int NC = Ci >> 5;
  int j = i & 7, lane = (i >> 3) & 63, r = i >> 9;
  int mt = r % TMT; r /= TMT;
  int cic = r % NC; r /= NC;
  int T = r % 16;   int coG = r / 16;
  int phx = T >> 2, t = T & 3;
  int dy = phx >> 1, dx = phx & 1, ty = t >> 1, tx = t & 1;
  int ky = 2 * ty + 1 - dy, kx = 2 * tx + 1 - dx;
  int co = coG * (TMT * 16) + mt * 16 + (lane & 15);
  int ci = cic * 32 + (lane >> 4) * 8 + j;
  float wv = (co < CoR) ? w[(((size_t)ci * CoR + co) * 4 + ky) * 4 + kx] : 0.f;
  p[i] = f2bf(wv);
}

__global__ __launch_bounds__(256) void k_pack_e1(
    const float* __restrict__ w, unsigned short* __restrict__ p) {
  int i = blockIdx.x * 256 + threadIdx.x;
  int j = i & 7, lane = (i >> 3) & 63, r = i >> 9;
  int mt = r % 8; r /= 8;
  int sp = r % 2; r /= 2;
  int cic = r;
  int co = mt * 16 + (lane & 15);
  int kk = cic * 32 + (lane >> 4) * 8 + j;
  int tap = kk >> 2, c = kk & 3;
  float wv = (c < 3) ? w[(((size_t)co * 3 + c) * 4 + (tap >> 2)) * 4 + (tap & 3)] : 0.f;
  unsigned short hv = f2bf(wv);
  p[i] = (sp == 1) ? f2bf(wv - bf2f(hv)) : hv;
}

// ================= fp32 kernels (tier-3 fallback) =========================
template<int COB, bool RELU_OUT>
__global__ __launch_bounds__(256) void k_conv4(
    const float* __restrict__ in, const float* __restrict__ w,
    const float* __restrict__ bias, float* __restrict__ out,
    int N, int Ci, int Hi, int Wi, int Co) {
  const int Ho = Hi >> 1, Wo = Wi >> 1;
  const int ow = blockIdx.x * 16 + (threadIdx.x & 15);
  const int oh = blockIdx.y * 16 + (threadIdx.x >> 4);
  const int zcnt = Co / COB;
  const int co0 = (blockIdx.z % zcnt) * COB;
  const int n   = blockIdx.z / zcnt;
  if (oh >= Ho || ow >= Wo) return;
  const float* __restrict__ ip = in + (size_t)n * Ci * Hi * Wi;
  float acc[COB];
#pragma unroll
  for (int j = 0; j < COB; ++j) acc[j] = bias[co0 + j];
  const int ih0 = 2 * oh - 1, iw0 = 2 * ow - 1;
  for (int ci = 0; ci < Ci; ++ci) {
    const float* __restrict__ ic = ip + (size_t)ci * Hi * Wi;
    float v[16];
#pragma unroll
    for (int kh = 0; kh < 4; ++kh) {
      const int ih = ih0 + kh;
      const bool hok = (unsigned)ih < (unsigned)Hi;
      const float* __restrict__ irow = ic + (long)ih * Wi;
#pragma unroll
      for (int kw = 0; kw < 4; ++kw) {
        const int iw = iw0 + kw;
        v[kh * 4 + kw] = (hok && (unsigned)iw < (unsigned)Wi) ? irow[iw] : 0.f;
      }
    }
#pragma unroll
    for (int j = 0; j < COB; ++j) {
      const float* __restrict__ wc = w + ((size_t)(co0 + j) * Ci + ci) * 16;
#pragma unroll
      for (int t = 0; t < 16; ++t) acc[j] = fmaf(v[t], wc[t], acc[j]);
    }
  }
#pragma unroll
  for (int j = 0; j < COB; ++j) {
    float a = acc[j];
    if (RELU_OUT) a = fmaxf(a, 0.f);
    out[(((size_t)n * Co + co0 + j) * Ho + oh) * Wo + ow] = a;
  }
}

template<int COB, bool RELU_IN, int CSPLIT>
__global__ __launch_bounds__(256) void k_conv3(
    const float* __restrict__ in, const float* __restrict__ w,
    float* __restrict__ out, int N, int Ci, int H, int W, int Co) {
  const int ow = blockIdx.x * 16 + (threadIdx.x & 15);
  const int oh = blockIdx.y * 16 + (threadIdx.x >> 4);
  const int zcnt = Co / COB;
  const int z = blockIdx.z;
  const int cs  = z % CSPLIT;
  const int co0 = ((z / CSPLIT) % zcnt) * COB;
  const int n   = z / (CSPLIT * zcnt);
  if (oh >= H || ow >= W) return;
  const int CPS = Ci / CSPLIT;
  const float* __restrict__ ip = in + (size_t)n * Ci * H * W;
  float acc[COB];
#pragma unroll
  for (int j = 0; j < COB; ++j) acc[j] = 0.f;
  for (int ci = cs * CPS; ci < (cs + 1) * CPS; ++ci) {
    const float* __restrict__ ic = ip + (size_t)ci * H * W;
    float v[9];
#pragma unroll
    for (int kh = 0; kh < 3; ++kh) {
      const int ih = oh - 1 + kh;
      const bool hok = (unsigned)ih < (unsigned)H;
      const float* __restrict__ irow = ic + (long)ih * W;
#pragma unroll
      for (int kw = 0; kw < 3; ++kw) {
        const int iw = ow - 1 + kw;
        float t = (hok && (unsigned)iw < (unsigned)W) ? irow[iw] : 0.f;
        if (RELU_IN) t = fmaxf(t, 0.f);
        v[kh * 3 + kw] = t;
      }
    }
#pragma unroll
    for (int j = 0; j < COB; ++j) {
      const float* __restrict__ wc = w + ((size_t)(co0 + j) * Ci + ci) * 9;
#pragma unroll
      for (int t = 0; t < 9; ++t) acc[j] = fmaf(v[t], wc[t], acc[j]);
    }
  }
#pragma unroll
  for (int j = 0; j < COB; ++j) {
    size_t oi = (((size_t)n * Co + co0 + j) * H + oh) * W + ow;
    if (CSPLIT > 1) atomicAdd(&out[oi], acc[j]);
    else out[oi] = acc[j];
  }
}

template<int COB, bool RELU_IN, bool ACCUM>
__global__ __launch_bounds__(256) void k_conv1(
    const float* __restrict__ in, const float* __restrict__ w,
    const float* __restrict__ bias, float* __restrict__ out,
    int N, int Ci, int P, int Co) {
  const int p = blockIdx.x * 256 + threadIdx.x;
  const int co0 = blockIdx.y * COB;
  const int n = blockIdx.z;
  if (p >= P) return;
  float acc[COB];
#pragma unroll
  for (int j = 0; j < COB; ++j) acc[j] = bias ? bias[co0 + j] : 0.f;
  const float* __restrict__ ip = in + (size_t)n * Ci * P + p;
#pragma unroll 8
  for (int ci = 0; ci < Ci; ++ci) {
    float v = ip[(size_t)ci * P];
    if (RELU_IN) v = fmaxf(v, 0.f);
#pragma unroll
    for (int j = 0; j < COB; ++j)
      acc[j] = fmaf(v, w[(size_t)(co0 + j) * Ci + ci], acc[j]);
  }
#pragma unroll
  for (int j = 0; j < COB; ++j) {
    size_t oi = ((size_t)n * Co + co0 + j) * P + p;
    if (ACCUM) out[oi] += acc[j]; else out[oi] = acc[j];
  }
}

template<int COB, bool RELU_IN, bool RELU_OUT>
__global__ __launch_bounds__(256) void k_convT(
    const float* __restrict__ in, const float* __restrict__ w,
    const float* __restrict__ bias, float* __restrict__ out,
    int N, int Ci, int Hi, int Wi, int Co) {
  const int Ho = Hi * 2, Wo = Wi * 2;
  const int x = blockIdx.x * 16 + (threadIdx.x & 15);
  const int y = blockIdx.y * 16 + (threadIdx.x >> 4);
  const int zcnt = Co / COB;
  const int co0 = (blockIdx.z % zcnt) * COB;
  const int n   = blockIdx.z / zcnt;
  if (x >= Wi || y >= Hi) return;
  const float* __restrict__ ip = in + (size_t)n * Ci * Hi * Wi;
  float a00[COB], a01[COB], a10[COB], a11[COB];
#pragma unroll
  for (int j = 0; j < COB; ++j) {
    float b = bias[co0 + j];
    a00[j] = b; a01[j] = b; a10[j] = b; a11[j] = b;
  }
  const bool r0 = y > 0, r2 = y + 1 < Hi, c0 = x > 0, c2 = x + 1 < Wi;
#pragma unroll 2
  for (int ci = 0; ci < Ci; ++ci) {
    const float* __restrict__ ic = ip + (size_t)ci * Hi * Wi + (size_t)y * Wi + x;
    float v00 = 0.f, v01 = 0.f, v02 = 0.f, v10 = 0.f, v12 = 0.f,
          v20 = 0.f, v21 = 0.f, v22 = 0.f;
    float v11 = ic[0];
    if (c0) v10 = ic[-1];
    if (c2) v12 = ic[1];
    if (r0) { v01 = ic[-Wi]; if (c0) v00 = ic[-Wi - 1]; if (c2) v02 = ic[-Wi + 1]; }
    if (r2) { v21 = ic[Wi];  if (c0) v20 = ic[Wi - 1];  if (c2) v22 = ic[Wi + 1]; }
    if (RELU_IN) {
      v00 = fmaxf(v00, 0.f); v01 = fmaxf(v01, 0.f); v02 = fmaxf(v02, 0.f);
      v10 = fmaxf(v10, 0.f); v11 = fmaxf(v11, 0.f); v12 = fmaxf(v12, 0.f);
      v20 = fmaxf(v20, 0.f); v21 = fmaxf(v21, 0.f); v22 = fmaxf(v22, 0.f);
    }
#pragma unroll
    for (int j = 0; j < COB; ++j) {
      const float* __restrict__ wc = w + ((size_t)ci * Co + co0 + j) * 16;
      a00[j] = fmaf(v11, wc[5],  fmaf(v10, wc[7],  fmaf(v01, wc[13], fmaf(v00, wc[15], a00[j]))));
      a01[j] = fmaf(v12, wc[4],  fmaf(v11, wc[6],  fmaf(v02, wc[12], fmaf(v01, wc[14], a01[j]))));
      a10[j] = fmaf(v21, wc[1],  fmaf(v20, wc[3],  fmaf(v11, wc[9],  fmaf(v10, wc[11], a10[j]))));
      a11[j] = fmaf(v22, wc[0],  fmaf(v21, wc[2],  fmaf(v12, wc[8],  fmaf(v11, wc[10], a11[j]))));
    }
  }
#pragma unroll
  for (int j = 0; j < COB; ++j) {
    size_t b = ((size_t)n * Co + co0 + j) * Ho;
    float o00 = a00[j], o01 = a01[j], o10 = a10[j], o11 = a11[j];
    if (RELU_OUT) {
      o00 = fmaxf(o00, 0.f); o01 = fmaxf(o01, 0.f);
      o10 = fmaxf(o10, 0.f); o11 = fmaxf(o11, 0.f);
    }
    out[(b + 2 * y) * Wo + 2 * x]         = o00;
    out[(b + 2 * y) * Wo + 2 * x + 1]     = o01;
    out[(b + 2 * y + 1) * Wo + 2 * x]     = o10;
    out[(b + 2 * y + 1) * Wo + 2 * x + 1] = o11;
  }
}

// ---- VQ full-batch (adds prevq bias qb on read) --------------------------
__global__ __launch_bounds__(256, 2) void k_vq(
    const float* __restrict__ ze, const float* __restrict__ emb,
    const float* __restrict__ qb,
    float* __restrict__ zq, float* __restrict__ loss) {
  __shared__ float e2s[512];
  const int tid = threadIdx.x;
  for (int k = tid; k < 512; k += 256) {
    const f32x4* e4 = (const f32x4*)(emb + (size_t)k * 64);
    float s = 0.f;
#pragma unroll
    for (int dq = 0; dq < 16; ++dq) {
      f32x4 ev = e4[dq];
      s = fmaf(ev[0], ev[0], s); s = fmaf(ev[1], ev[1], s);
      s = fmaf(ev[2], ev[2], s); s = fmaf(ev[3], ev[3], s);
    }
    e2s[k] = s;
  }
  __syncthreads();
  const int p = blockIdx.x * 256 + tid;
  const int n = p >> 10, px = p & 1023;
  float xv[64];
  const float* __restrict__ zp = ze + (size_t)n * 64 * 1024 + px;
#pragma unroll
  for (int d = 0; d < 64; ++d) xv[d] = zp[(size_t)d * 1024] + (qb ? qb[d] : 0.f);
  float best = 1e30f; int bi = 0;
  for (int k = 0; k < 512; ++k) {
    const f32x4* e4 = (const f32x4*)(emb + (size_t)k * 64);
    float dot = 0.f;
#pragma unroll
    for (int dq = 0; dq < 16; ++dq) {
      f32x4 ev = e4[dq];
      dot = fmaf(xv[4 * dq],     ev[0], dot);
      dot = fmaf(xv[4 * dq + 1], ev[1], dot);
      dot = fmaf(xv[4 * dq + 2], ev[2], dot);
      dot = fmaf(xv[4 * dq + 3], ev[3], dot);
    }
    float sc = fmaf(-2.f, dot, e2s[k]);
    if (sc < best) { best = sc; bi = k; }
  }
  const float* __restrict__ eb = emb + (size_t)bi * 64;
  float* __restrict__ qp = zq + (size_t)n * 64 * 1024 + px;
  float l = 0.f;
#pragma unroll
  for (int d = 0; d < 64; ++d) {
    float ev = eb[d];
    qp[(size_t)d * 1024] = ev;
    float df = ev - xv[d];
    l = fmaf(df, df, l);
  }
#pragma unroll
  for (int off = 32; off > 0; off >>= 1) l += __shfl_down(l, off, 64);
  if ((tid & 63) == 0) atomicAdd(loss, l * (2.f / 2097152.f));
}

__global__ __launch_bounds__(64) void k_vq64(
    const float* __restrict__ ze, const float* __restrict__ emb,
    float* __restrict__ zq, float* __restrict__ loss,
    int N, int P, int K) {
  const int t = blockIdx.x * 64 + threadIdx.x;
  if (t >= N * P) return;
  const int n = t / P, p = t % P;
  float xv[64];
  const float* __restrict__ zp = ze + (size_t)n * 64 * P + p;
#pragma unroll
  for (int d = 0; d < 64; ++d) xv[d] = zp[(size_t)d * P];
  float best = 1e30f; int bi = 0;
  for (int k = 0; k < K; ++k) {
    const float* __restrict__ e = emb + (size_t)k * 64;
    float dot = 0.f, e2 = 0.f;
#pragma unroll
    for (int d = 0; d < 64; ++d) {
      float ev = e[d];
      dot = fmaf(xv[d], ev, dot);
      e2  = fmaf(ev, ev, e2);
    }
    float score = e2 - 2.f * dot;
    if (score < best) { best = score; bi = k; }
  }
  const float* __restrict__ eb = emb + (size_t)bi * 64;
  float* __restrict__ qp = zq + (size_t)n * 64 * P + p;
  float l = 0.f;
#pragma unroll
  for (int d = 0; d < 64; ++d) {
    float ev = eb[d];
    qp[(size_t)d * P] = ev;
    float df = ev - xv[d];
    l = fmaf(df, df, l);
  }
#pragma unroll
  for (int off = 32; off > 0; off >>= 1) l += __shfl_down(l, off, 64);
  if ((threadIdx.x & 63) == 0) atomicAdd(loss, l * (2.f / 2097152.f));
}

extern "C" void kernel_launch(void* const* d_in, const int* in_sizes, int n_in,
                              void* d_out, int out_size, void* d_ws, size_t ws_size,
                              hipStream_t stream) {
  const float* x    = (const float*)d_in[0];
  const float* ew1  = (const float*)d_in[1];
  const float* eb1  = (const float*)d_in[2];
  const float* ew2  = (const float*)d_in[3];
  const float* eb2  = (const float*)d_in[4];
  const float* ew3  = (const float*)d_in[5];
  const float* eb3  = (const float*)d_in[6];
  const float* erw3 = (const float*)d_in[7];
  const float* erw1 = (const float*)d_in[8];
  const float* pqw  = (const float*)d_in[9];
  const float* pqb  = (const float*)d_in[10];
  const float* emb  = (const float*)d_in[11];
  const float* dw1  = (const float*)d_in[12];
  const float* db1  = (const float*)d_in[13];
  const float* drw3 = (const float*)d_in[14];
  const float* drw1 = (const float*)d_in[15];
  const float* dw2  = (const float*)d_in[16];
  const float* db2  = (const float*)d_in[17];
  const float* dw3  = (const float*)d_in[18];
  const float* db3  = (const float*)d_in[19];
  float* out = (float*)d_out;
  char*  ws  = (char*)d_ws;
  float* loss = out + 6291456;
  const size_t MiB = 1048576ull, KiB = 1024ull;

  dim3 blk(256);
  hipMemsetAsync(loss, 0, 4, stream);

  unsigned syct = 0, sxct = 0;
  for (int T = 0; T < 16; ++T) {
    int phx = T >> 2, dy = phx >> 1, dx = phx & 1, t = T & 3, ty = t >> 1, tx = t & 1;
    int sy = (dy == 0) ? (ty ? -1 : 0) : (ty ? 0 : 1);
    int sx = (dx == 0) ? (tx ? -1 : 0) : (tx ? 0 : 1);
    syct |= (unsigned)(sy + 1) << (2 * T);
    sxct |= (unsigned)(sx + 1) << (2 * T);
  }
  unsigned syc3 = 0, sxc3 = 0;
  for (int t = 0; t < 9; ++t) {
    syc3 |= (unsigned)(t / 3) << (2 * t);
    sxc3 |= (unsigned)(t % 3) << (2 * t);
  }
  unsigned syc4 = 0, sxc4 = 0;
  for (int t = 0; t < 16; ++t) {
    syc4 |= (unsigned)(t / 4) << (2 * t);
    sxc4 |= (unsigned)(t % 4) << (2 * t);
  }
  const unsigned sy1 = 1, sx1 = 1;

  // pack region layout (KiB offsets within PB; PB spans 484..498 MiB tier1)
  auto packs = [&](char* PB) {
    unsigned short* e2p   = (unsigned short*)(PB);
    unsigned short* e3p   = (unsigned short*)(PB + 2048 * KiB);
    unsigned short* erc3p = (unsigned short*)(PB + 10240 * KiB);
    unsigned short* erc1p = (unsigned short*)(PB + 10816 * KiB);
    unsigned short* pqp   = (unsigned short*)(PB + 10880 * KiB);
    unsigned short* d1p   = (unsigned short*)(PB + 11008 * KiB);
    unsigned short* d2p   = (unsigned short*)(PB + 11520 * KiB);
    unsigned short* dc3p  = (unsigned short*)(PB + 12544 * KiB);
    unsigned short* dc1p  = (unsigned short*)(PB + 12688 * KiB);
    unsigned short* e1p   = (unsigned short*)(PB + 12704 * KiB);
    unsigned short* d3p   = (unsigned short*)(PB + 12832 * KiB);
    unsigned short* erc1F = (unsigned short*)(PB + 12960 * KiB);
    unsigned short* dc1F  = (unsigned short*)(PB + 13024 * KiB);
    k_pack_o<true ><<<dim3(1048576 / 256), blk, 0, stream>>>(ew2,  e2p,  256, 128, 16, 8, 1048576);
    k_pack_o<true ><<<dim3(4194304 / 256), blk, 0, stream>>>(ew3,  e3p,  512, 256, 16, 8, 4194304);
    k_pack_o<true ><<<dim3(294912 / 256),  blk, 0, stream>>>(erw3, erc3p, 32, 512,  9, 2, 294912);
    k_pack_o<true ><<<dim3(32768 / 256),   blk, 0, stream>>>(erw1, erc1p, 512, 32,  1, 8, 32768);
    k_pack_o<true ><<<dim3(65536 / 256),   blk, 0, stream>>>(pqw,  pqp,   64, 512,  1, 4, 65536);
    k_pack_ct<<<dim3(262144 / 256), blk, 0, stream>>>(dw1, d1p, 64, 256, 8, 262144);
    k_pack_ct<<<dim3(524288 / 256), blk, 0, stream>>>(dw2, d2p, 256, 128, 8, 524288);
    k_pack_o<false><<<dim3(73728 / 256),   blk, 0, stream>>>(drw3, dc3p,  32, 256,  9, 2, 73728);
    k_pack_o<false><<<dim3(8192 / 256),    blk, 0, stream>>>(drw1, dc1p, 256, 32,  1, 8, 8192);
    k_pack_e1<<<dim3(256), blk, 0, stream>>>(ew1, e1p);
    k_pack_ct<<<dim3(65536 / 256), blk, 0, stream>>>(dw3, d3p, 128, 3, 2, 65536);
    k_pack_o<true ><<<dim3(32768 / 256), blk, 0, stream>>>(erw1, erc1F, 512, 32, 1, 32, 32768);
    k_pack_o<false><<<dim3(8192 / 256),  blk, 0, stream>>>(drw1, dc1F, 256, 32, 1, 16, 8192);
  };

  if (ws_size >= 498ull * MiB) {
    // ============ Tier 1: full batch (R8 schedule + fused res) ============
    // z1@0(256) z2@256(128) z3@384(64) z3b@0(64,z1 dead) ze@452 zq@460
    // dec: y1@256(128,z2 dead) y1b@0(128) y2@0(256,y1b dead) PB@484
    float* z1  = (float*)ws;
    float* z2  = (float*)(ws + 256 * MiB);
    float* z3  = (float*)(ws + 384 * MiB);
    float* z3b = (float*)ws;
    float* ze  = (float*)(ws + 452 * MiB);
    float* zq  = (float*)(ws + 460 * MiB);
    char*  PB  = ws + 484 * MiB;
    unsigned short* e2p   = (unsigned short*)(PB);
    unsigned short* e3p   = (unsigned short*)(PB + 2048 * KiB);
    unsigned short* erc3p = (unsigned short*)(PB + 10240 * KiB);
    unsigned short* pqp   = (unsigned short*)(PB + 10880 * KiB);
    unsigned short* d1p   = (unsigned short*)(PB + 11008 * KiB);
    unsigned short* d2p   = (unsigned short*)(PB + 11520 * KiB);
    unsigned short* dc3p  = (unsigned short*)(PB + 12544 * KiB);
    unsigned short* e1p   = (unsigned short*)(PB + 12704 * KiB);
    unsigned short* d3p   = (unsigned short*)(PB + 12832 * KiB);
    unsigned short* erc1F = (unsigned short*)(PB + 12960 * KiB);
    unsigned short* dc1F  = (unsigned short*)(PB + 13024 * KiB);
    packs(PB);

    // encoder
    k_mfenc1<<<dim3(8192), blk, 0, stream>>>(x, e1p, eb1, z1);
    k_mfconv<4, 2, 2, 1, true, false, true, true, 0><<<dim3(2048, 2), blk, 0, stream>>>(
        z1, e2p, eb2, z2, 128, 128, 128, 6, 12, 256, 16, 16, syc4, sxc4, 64, 4096, 256);
    k_mfconv<4, 2, 2, 1, true, false, false, true, 0><<<dim3(512, 4), blk, 0, stream>>>(
        z2, e3p, eb3, z3, 256, 64, 64, 5, 10, 512, 16, 16, syc4, sxc4, 32, 1024, 512);
    // res stack (fused, ping-pong z3 <-> z3b)
    k_mfres<8, true><<<dim3(512), blk, 0, stream>>>(z3,  erc3p, erc1F, z3b, 5, 10, syc3, sxc3);
    k_mfres<8, true><<<dim3(512), blk, 0, stream>>>(z3b, erc3p, erc1F, z3,  5, 10, syc3, sxc3);
    // prevq + VQ
    hipMemsetAsync(ze, 0, 8 * MiB, stream);
    k_mfconv<4, 1, 0, 4, true, true, false, false, 2><<<dim3(512, 1, 4), blk, 0, stream>>>(
        z3, pqp, nullptr, ze, 512, 32, 32, 5, 10, 64, 1, 1, sy1, sx1, 32, 1024, 64);
    k_vq<<<dim3(128), blk, 0, stream>>>(ze, emb, pqb, zq, loss);
    // decoder
    float* y1  = (float*)(ws + 256 * MiB);
    float* y1b = (float*)ws;
    float* y2  = (float*)ws;
    k_mfconv<4, 2, 1, 1, false, false, false, true, 0><<<dim3(512, 2, 4), blk, 0, stream>>>(
        zq, d1p, db1, y1, 64, 32, 32, 5, 10, 256, 4, 16, syct, sxct, 64, 4096, 256);
    k_mfres<4, false><<<dim3(2048), blk, 0, stream>>>(y1,  dc3p, dc1F, y1b, 6, 12, syc3, sxc3);
    k_mfres<4, false><<<dim3(2048), blk, 0, stream>>>(y1b, dc3p, dc1F, y1,  6, 12, syc3, sxc3);
    k_mfconv<4, 2, 1, 1, false, true, true, true, 0><<<dim3(2048, 1, 4), blk, 0, stream>>>(
        y1, d2p, db2, y2, 256, 64, 64, 6, 12, 128, 4, 16, syct, sxct, 128, 16384, 128);
    k_mfconv<2, 1, 1, 1, false, false, false, true, 0><<<dim3(8192, 1, 4), blk, 0, stream>>>(
        y2, d3p, db3, out, 128, 128, 128, 7, 14, 3, 4, 16, syct, sxct, 256, 65536, 3);
    return;
  }

  if (ws_size >= 128ull * MiB) {
    // ============ Tier 2: chunked (R8, unchanged) ============
    float* z3  = (float*)ws;
    float* h   = (float*)(ws + 64 * MiB);
    float* ze  = (float*)(ws + 68 * MiB);
    float* zq  = (float*)(ws + 100 * MiB);
    char*  PB  = ws + 115 * MiB;
    unsigned short* e2p   = (unsigned short*)(PB);
    unsigned short* e3p   = (unsigned short*)(PB + 2048 * KiB);
    unsigned short* erc3p = (unsigned short*)(PB + 10240 * KiB);
    unsigned short* erc1p = (unsigned short*)(PB + 10816 * KiB);
    unsigned short* pqp   = (unsigned short*)(PB + 10880 * KiB);
    unsigned short* d1p   = (unsigned short*)(PB + 11008 * KiB);
    unsigned short* d2p   = (unsigned short*)(PB + 11520 * KiB);
    unsigned short* dc3p  = (unsigned short*)(PB + 12544 * KiB);
    unsigned short* dc1p  = (unsigned short*)(PB + 12688 * KiB);
    unsigned short* e1p   = (unsigned short*)(PB + 12704 * KiB);
    unsigned short* d3p   = (unsigned short*)(PB + 12832 * KiB);
    packs(PB);

    const int NE = 4;
    float* z1c = (float*)(ws + 64 * MiB);
    float* z2c = (float*)(ws + 96 * MiB);
    for (int n0 = 0; n0 < 32; n0 += NE) {
      const float* xb = x + (size_t)n0 * 3 * 65536;
      float* z3b2 = z3 + (size_t)n0 * 512 * 1024;
      k_mfenc1<<<dim3(NE * 256), blk, 0, stream>>>(xb, e1p, eb1, z1c);
      k_mfconv<4, 2, 2, 1, true, false, true, true, 0><<<dim3(256, 2), blk, 0, stream>>>(
          z1c, e2p, eb2, z2c, 128, 128, 128, 6, 12, 256, 16, 16, syc4, sxc4, 64, 4096, 256);
      k_mfconv<4, 2, 2, 1, true, false, false, true, 0><<<dim3(64, 4), blk, 0, stream>>>(
          z2c, e3p, eb3, z3b2, 256, 64, 64, 5, 10, 512, 16, 16, syc4, sxc4, 32, 1024, 512);
    }
    for (int i = 0; i < 2; ++i) {
      hipMemsetAsync(h, 0, 4 * MiB, stream);
      k_mfconv<2, 1, 0, 3, true, true, false, false, 2><<<dim3(512, 1, 3), blk, 0, stream>>>(
          z3, erc3p, nullptr, h, 512, 32, 32, 5, 10, 32, 9, 9, syc3, sxc3, 32, 1024, 32);
      k_mfconv<4, 2, 0, 1, true, true, false, false, 1><<<dim3(512, 4), blk, 0, stream>>>(
          h, erc1p, nullptr, z3, 32, 32, 32, 5, 10, 512, 1, 1, sy1, sx1, 32, 1024, 512);
    }
    hipMemsetAsync(ze, 0, 8 * MiB, stream);
    k_mfconv<4, 1, 0, 4, true, true, false, false, 2><<<dim3(512, 1, 4), blk, 0, stream>>>(
        z3, pqp, nullptr, ze, 512, 32, 32, 5, 10, 64, 1, 1, sy1, sx1, 32, 1024, 64);
    k_vq<<<dim3(128), blk, 0, stream>>>(ze, emb, pqb, zq, loss);

    const int ND = 8;
    float* y1c = (float*)ws;
    float* hd  = (float*)(ws + 32 * MiB);
    float* y2c = (float*)(ws + 36 * MiB);
    for (int c = 0; c < 32; c += ND) {
      const float* zqb = zq + (size_t)c * 64 * 1024;
      float* outb = out + (size_t)c * 3 * 65536;
      k_mfconv<4, 2, 1, 1, false, false, false, true, 0><<<dim3(128, 2, 4), blk, 0, stream>>>(
          zqb, d1p, db1, y1c, 64, 32, 32, 5, 10, 256, 4, 16, syct, sxct, 64, 4096, 256);
      for (int i = 0; i < 2; ++i) {
        hipMemsetAsync(hd, 0, 4 * MiB, stream);
        k_mfconv<2, 1, 0, 3, false, true, false, false, 2><<<dim3(512, 1, 3), blk, 0, stream>>>(
            y1c, dc3p, nullptr, hd, 256, 64, 64, 6, 12, 32, 9, 9, syc3, sxc3, 64, 4096, 32);
        k_mfconv<4, 2, 0, 1, false, true, false, false, 1><<<dim3(512, 2), blk, 0, stream>>>(
            hd, dc1p, nullptr, y1c, 32, 64, 64, 6, 12, 256, 1, 1, sy1, sx1, 64, 4096, 256);
      }
      k_mfconv<4, 2, 1, 1, false, true, true, true, 0><<<dim3(512, 1, 4), blk, 0, stream>>>(
          y1c, d2p, db2, y2c, 256, 64, 64, 6, 12, 128, 4, 16, syct, sxct, 128, 16384, 128);
      k_mfconv<2, 1, 1, 1, false, false, false, true, 0><<<dim3(2048, 1, 4), blk, 0, stream>>>(
          y2c, d3p, db3, outb, 128, 128, 128, 7, 14, 3, 4, 16, syct, sxct, 256, 65536, 3);
    }
    return;
  }

  // ============ Tier 3 fallback (fp32) ============
  const size_t PER_IMG = 12582912ull;
  int NB = (int)(ws_size / PER_IMG);
  if (NB > 32) NB = 32;
  if (NB < 1)  NB = 1;

  for (int n0 = 0; n0 < 32; n0 += NB) {
    const int nb = (32 - n0 < NB) ? (32 - n0) : NB;
    const float* xb   = x   + (size_t)n0 * 3 * 65536;
    float*       outb = out + (size_t)n0 * 3 * 65536;

    float* z1 = (float*)ws;
    float* z2 = (float*)(ws + (size_t)NB * 8388608ull);
    float* z3 = (float*)ws;
    char*  tb = ws + (size_t)NB * 2097152ull;
    float* he = (float*)tb;
    float* ze = (float*)(tb + (size_t)NB * 131072ull);
    float* zq = (float*)(tb + (size_t)NB * 393216ull);
    float* hd = (float*)(tb + (size_t)NB * 655360ull);
    float* y1 = z2;
    float* y2 = (float*)ws;

    k_conv4<4, true ><<<dim3(8, 8, nb * 32), blk, 0, stream>>>(xb, ew1, eb1, z1, nb,   3, 256, 256, 128);
    k_conv4<4, true ><<<dim3(4, 4, nb * 64), blk, 0, stream>>>(z1, ew2, eb2, z2, nb, 128, 128, 128, 256);
    k_conv4<4, false><<<dim3(2, 2, nb * 128), blk, 0, stream>>>(z2, ew3, eb3, z3, nb, 256,  64,  64, 512);
    for (int i = 0; i < 2; ++i) {
      k_conv3<4, true, 1><<<dim3(2, 2, nb * 8), blk, 0, stream>>>(z3, erw3, he, nb, 512, 32, 32, 32);
      k_conv1<8, true, true><<<dim3(4, 64, nb), blk, 0, stream>>>(he, erw1, nullptr, z3, nb, 32, 1024, 512);
    }
    k_conv1<8, true, false><<<dim3(4, 8, nb), blk, 0, stream>>>(z3, pqw, pqb, ze, nb, 512, 1024, 64);
    k_vq64<<<dim3(nb * 16), dim3(64), 0, stream>>>(ze, emb, zq, loss, nb, 1024, 512);
    k_convT<4, false, false><<<dim3(2, 2, nb * 64), blk, 0, stream>>>(zq, dw1, db1, y1, nb,  64, 32, 32, 256);
    for (int i = 0; i < 2; ++i) {
      k_conv3<4, true, 1><<<dim3(4, 4, nb * 8), blk, 0, stream>>>(y1, drw3, hd, nb, 256, 64, 64, 32);
      k_conv1<8, true, true><<<dim3(16, 32, nb), blk, 0, stream>>>(hd, drw1, nullptr, y1, nb, 32, 4096, 256);
    }
    k_convT<4, true, true ><<<dim3(4, 4, nb * 32), blk, 0, stream>>>(y1, dw2, db2, y2, nb, 256, 64, 64, 128);
    k_convT<1, false, false><<<dim3(8, 8, nb * 3), blk, 0, stream>>>(y2, dw3, db3, outb, nb, 128, 128, 128, 3);
  }
}